// Round 9
// baseline (324.052 us; speedup 1.0000x reference)
//
#include <hip/hip_runtime.h>

#define H_ 32
#define E_ 32
#define C_ 1024
#define L_ 1024
#define N_ 4
#define M_ 4096      // N_*L_
#define NH_ 128      // N_*H_
#define D_ 257
#define DPAD 272     // demb padded rows (zeros beyond 256)
#define TEMP_ 0.17677669529663687f
#define QSCALE_ (TEMP_ * 1.4426950408889634f)   // temp * log2(e), folded into q & KD

typedef unsigned short u16;
typedef __attribute__((ext_vector_type(8))) short short8;
typedef __attribute__((ext_vector_type(4))) float f32x4;
typedef __attribute__((ext_vector_type(4))) unsigned short u16x4;

__device__ __forceinline__ u16 f2bf(float f) {
  union { float f; unsigned u; } v; v.f = f;
  unsigned r = v.u + 0x7fffu + ((v.u >> 16) & 1u);
  return (u16)(r >> 16);
}
__device__ __forceinline__ float bf2f(u16 h) {
  union { unsigned u; float f; } v; v.u = ((unsigned)h) << 16;
  return v.f;
}
__device__ __forceinline__ f32x4 mfma16(short8 a, short8 b, f32x4 c) {
  return __builtin_amdgcn_mfma_f32_16x16x32_bf16(a, b, c, 0, 0, 0);
}
__device__ __forceinline__ float ex2(float x) {
#if __has_builtin(__builtin_amdgcn_exp2f)
  return __builtin_amdgcn_exp2f(x);
#else
  float r;
  asm("v_exp_f32 %0, %1\n\ts_nop 1" : "=v"(r) : "v"(x));
  return r;
#endif
}
// async global->LDS, 16B per lane; lds base must be wave-uniform
__device__ __forceinline__ void gld16(const u16* g, u16* l) {
  __builtin_amdgcn_global_load_lds(
      (const __attribute__((address_space(1))) unsigned int*)g,
      (__attribute__((address_space(3))) unsigned int*)l, 16, 0, 0);
}

// ---- misc: x->bf16 conversion + dist_emb->bf16 (padded) + qkv bias pack ----
__global__ __launch_bounds__(256) void misc_kernel(
    const float* __restrict__ x, const float* __restrict__ demb,
    const float* __restrict__ bq, const float* __restrict__ bk,
    const float* __restrict__ bv, u16* __restrict__ xb,
    u16* __restrict__ demb_b, float* __restrict__ bqkv) {
  const int b = blockIdx.x, tid = threadIdx.x;
  if (b < 4096) {
    int i = b * 256 + tid;
    f32x4 v = reinterpret_cast<const f32x4*>(x)[i];
    u16x4 o2;
    o2[0] = f2bf(v[0]); o2[1] = f2bf(v[1]); o2[2] = f2bf(v[2]); o2[3] = f2bf(v[3]);
    reinterpret_cast<u16x4*>(xb)[i] = o2;
  } else {
    int i = (b - 4096) * 256 + tid;
    if (i < DPAD * E_) demb_b[i] = (i < D_ * E_) ? f2bf(demb[i]) : (u16)0;
    if (i < C_) { bqkv[i] = bq[i]; bqkv[C_ + i] = bk[i]; bqkv[2 * C_ + i] = bv[i]; }
  }
}

// ---- 5 weight transposes in one launch: W (K x N) -> W^T (N x K) bf16 ----
__global__ __launch_bounds__(256) void transpose_w_kernel(
    const float* __restrict__ Wq, const float* __restrict__ Wk,
    const float* __restrict__ Wv, const float* __restrict__ W1,
    const float* __restrict__ W2, u16* __restrict__ out_base) {
  __shared__ float tile[32][33];
  const int z = blockIdx.z;
  const float* in = (z == 0) ? Wq : (z == 1) ? Wk : (z == 2) ? Wv : (z == 3) ? W1 : W2;
  u16* out = out_base + (size_t)z * C_ * C_;
  int j0 = blockIdx.x * 32, c0 = blockIdx.y * 32;
#pragma unroll
  for (int i = 0; i < 4; ++i) {
    int cy = threadIdx.y + i * 8;
    tile[cy][threadIdx.x] = in[(size_t)(c0 + cy) * C_ + j0 + threadIdx.x];
  }
  __syncthreads();
#pragma unroll
  for (int i = 0; i < 4; ++i) {
    int jy = threadIdx.y + i * 8;
    out[(size_t)(j0 + jy) * C_ + c0 + threadIdx.x] = f2bf(tile[threadIdx.x][jy]);
  }
}

// ---- GEMM: C[M x Ncols] = A[M x K] * Bt[Ncols x K]^T, bf16 in / fp32 acc ----
template <int EPI>
__global__ __launch_bounds__(256) void gemm128_kernel(
    const u16* __restrict__ A, const u16* __restrict__ Bt, int K,
    const float* __restrict__ bias,
    u16* __restrict__ out0, u16* __restrict__ out1, u16* __restrict__ out2) {
  __shared__ u16 As[128 * 64];
  __shared__ u16 Bs[128 * 64];
  const int bid = blockIdx.x;
  const int m0 = (bid & 31) << 7;
  const int n0 = (bid >> 5) << 7;
  const int tid = threadIdx.x;
  const int w = tid >> 6, lane = tid & 63, lhi = lane >> 4, llo = lane & 15;
  const int wr = w >> 1, wc = w & 1;
  const int w4 = w << 2;
  const int srow = lane >> 3, scol = (lane & 7) << 3;
  f32x4 acc[4][4] = {};
  for (int k0 = 0; k0 < K; k0 += 64) {
#pragma unroll
    for (int j = 0; j < 4; ++j) {
      const int seg = w4 + j;
      const int row = (seg << 3) + srow;
      gld16(&A[(size_t)(m0 + row) * K + k0 + scol], &As[seg << 9]);
      gld16(&Bt[(size_t)(n0 + row) * K + k0 + scol], &Bs[seg << 9]);
    }
    __syncthreads();
#pragma unroll
    for (int kk = 0; kk < 2; ++kk) {
      const int ko = (kk << 5) + lhi * 8;
      short8 af[4], bf[4];
#pragma unroll
      for (int mi = 0; mi < 4; ++mi)
        af[mi] = *reinterpret_cast<const short8*>(&As[(wr * 64 + mi * 16 + llo) * 64 + ko]);
#pragma unroll
      for (int ni = 0; ni < 4; ++ni)
        bf[ni] = *reinterpret_cast<const short8*>(&Bs[(wc * 64 + ni * 16 + llo) * 64 + ko]);
#pragma unroll
      for (int mi = 0; mi < 4; ++mi)
#pragma unroll
        for (int ni = 0; ni < 4; ++ni)
          acc[mi][ni] = mfma16(af[mi], bf[ni], acc[mi][ni]);
    }
    __syncthreads();
  }
#pragma unroll
  for (int mi = 0; mi < 4; ++mi)
#pragma unroll
    for (int ni = 0; ni < 4; ++ni)
#pragma unroll
      for (int r = 0; r < 4; ++r) {
        int row = m0 + wr * 64 + mi * 16 + lhi * 4 + r;
        int col = n0 + wc * 64 + ni * 16 + llo;
        float v = acc[mi][ni][r] + bias[col];
        if constexpr (EPI == 0) {
          int which = col >> 10, jj = col & 1023, h = jj >> 5, e2 = jj & 31;
          int n = row >> 10, l = row & 1023;
          int nh = (n << 5) | h;
          if (which == 0) v *= QSCALE_;   // fold temp*log2e into q
          u16 bvv = f2bf(v);
          if (which == 0)      out0[((size_t)((nh << 10) | l)) * 32 + e2] = bvv;
          else if (which == 1) out1[((size_t)((nh << 10) | l)) * 32 + e2] = bvv;
          else                 out2[(((size_t)(nh * 32 + e2)) << 10) | l] = bvv;
        } else if constexpr (EPI == 1) {
          out0[(size_t)row * C_ + col] = f2bf(fmaxf(v, 0.f));
        } else {
          out0[(size_t)row * C_ + col] = f2bf(v);
        }
      }
}

// ---- KD (banded): kdb[head][l][j] = QSCALE * k[s]·demb[d],  j = s-l+128,
// l = s+d-128, row stride 257 (flat = 256*l + s + 128). aux0/256 = d=0/256 rows.
__global__ __launch_bounds__(256) void qdkd_kernel(
    const u16* __restrict__ src, const u16* __restrict__ dembp,
    u16* __restrict__ kdb, u16* __restrict__ aux0, u16* __restrict__ aux256) {
  const int wt = blockIdx.x * 4 + (threadIdx.x >> 6);
  const int lane = threadIdx.x & 63, lhi = lane >> 4, llo = lane & 15;
  const int m0 = wt << 4;
  const int head = m0 >> 10;
  u16* kdbh = kdb + (size_t)head * ((size_t)L_ * D_);
  short8 a = *reinterpret_cast<const short8*>(&src[(size_t)(m0 + llo) * E_ + lhi * 8]);
#pragma unroll
  for (int ct = 0; ct < 17; ++ct) {
    int d = ct * 16 + llo;
    short8 b = *reinterpret_cast<const short8*>(&dembp[d * E_ + lhi * 8]);
    f32x4 c = {};
    c = mfma16(a, b, c);
    if (d < D_) {
#pragma unroll
      for (int r = 0; r < 4; ++r) {
        u16 val = f2bf(c[r] * QSCALE_);
        const int mrow = m0 + (lhi << 2) + r;
        const int sl = mrow & 1023;
        const int lp = sl + d - 128;
        if (lp >= 0 && lp < L_) kdbh[256 * lp + sl + 128] = val;
        if (d == 0)   aux0[mrow] = val;
        if (d == 256) aux256[mrow] = val;
      }
    }
  }
}

// ---- attention v9: banded KD (vector in-band loads) + reversed QD table ----
// Orientation mfma(K, Q): lane holds S[s=s0+lhi*4+r][q=lg].
// QDs[q][j] stores QD[q][256-j] (stride 257) -> in-band reads are ds_read_b64;
// kdb in-band reads are aligned u16x4. Classes: far / boundary / pure in-band
// (wave-uniform). Single P buffer; no barriers. LDS 36992 B -> 4 blocks/CU.
__global__ __launch_bounds__(256, 4) void attn_kernel(
    const u16* __restrict__ qw, const u16* __restrict__ kw,
    const u16* __restrict__ vT, const u16* __restrict__ dembp,
    const u16* __restrict__ kdb, const u16* __restrict__ kd0a,
    const u16* __restrict__ kd256a, u16* __restrict__ tb) {
  __shared__ u16 QDs[64 * 257];   // 32896 B, wave-local, reversed-d layout
  __shared__ u16 Pbuf[4 * 512];   // 4096 B: per-wave P round-trip (1KB each)
  const int bid = blockIdx.x;
  const int nh = bid & (NH_ - 1);     // XCD-friendly
  const int l0 = (bid >> 7) << 6;
  const int tid = threadIdx.x;
  const int w = tid >> 6, lane = tid & 63, lhi = lane >> 4, llo = lane & 15;
  const int lw0 = l0 + (w << 4);
  const int lg = lw0 + llo;
  const int lrow = (w << 4) + llo;    // this lane's q-row within QDs

  const u16* qb  = qw + (size_t)nh * (L_ * E_);
  const u16* kb  = kw + (size_t)nh * (L_ * E_);
  const u16* vb  = vT + (size_t)nh * (E_ * L_);
  const u16* kdl = kdb + (size_t)nh * ((size_t)L_ * D_) + 256 * (size_t)lg + 128;
  const u16* k0g = kd0a + (size_t)nh * L_;
  const u16* k2g = kd256a + (size_t)nh * L_;

  // q fragment (same lane layout works as MFMA A- and B-operand)
  const short8 qA = *(const short8*)&qb[(size_t)lg * E_ + lhi * 8];
  const int qr4 = (w << 4) + (lhi << 2);

  // in-kernel QD, reversed: QDs[q*257 + 256 - d]
#pragma unroll
  for (int dt = 0; dt < 16; ++dt) {
    short8 db = *(const short8*)&dembp[(dt * 16 + llo) * E_ + lhi * 8];
    f32x4 qd = {};
    qd = mfma16(qA, db, qd);
#pragma unroll
    for (int r = 0; r < 4; ++r)
      QDs[(qr4 + r) * 257 + 256 - (dt * 16 + llo)] = f2bf(qd[r]);
  }
  {
    short8 db = *(const short8*)&dembp[(size_t)(256 + llo) * E_ + lhi * 8];
    f32x4 qd = {};
    qd = mfma16(qA, db, qd);
    if (llo == 0) {
#pragma unroll
      for (int r = 0; r < 4; ++r) QDs[(qr4 + r) * 257 + 0] = f2bf(qd[r]);
    }
  }
  const int qrb = lrow * 257;            // this lane's QD row base
  const int qpb = qrb + 128 - lg;        // + scol = in-band j index (4-aligned)
  const float qd_d0   = bf2f(QDs[qrb + 256]);   // d=0
  const float qd_d256 = bf2f(QDs[qrb + 0]);     // d=256

  f32x4 o0 = {}, o1 = {};
  float lacc = 0.f;
  char* Pw = reinterpret_cast<char*>(&Pbuf[w * 512]);

  for (int s0 = 0; s0 < L_; s0 += 32) {
    short8 kA0 = *(const short8*)&kb[(size_t)(s0 + llo) * E_ + lhi * 8];
    short8 kA1 = *(const short8*)&kb[(size_t)(s0 + 16 + llo) * E_ + lhi * 8];
    f32x4 st0 = {}, st1 = {};
    st0 = mfma16(kA0, qA, st0);
    st1 = mfma16(kA1, qA, st1);

    float p[8];
    const int delta = lw0 - s0;
    if (delta >= 159 || delta <= -143) {
      // far: fully clamped -> per-q register + per-s clamp vectors
      const bool fh = delta >= 159;
      const float qdc = fh ? qd_d256 : qd_d0;
      const u16* kcg = fh ? k2g : k0g;
      u16x4 kc0 = *(const u16x4*)&kcg[s0 + lhi * 4];
      u16x4 kc1 = *(const u16x4*)&kcg[s0 + 16 + lhi * 4];
#pragma unroll
      for (int r = 0; r < 4; ++r) {
        p[r]     = ex2(st0[r] + qdc + bf2f(kc0[r]));
        p[4 + r] = ex2(st1[r] + qdc + bf2f(kc1[r]));
      }
    } else if (delta <= 112 && delta >= -97) {
      // pure in-band: 2x ds_read_b64 (QD) + 2x u16x4 (KD), all r-consecutive
      u16x4 qv0 = *(const u16x4*)&QDs[qpb + s0 + (lhi << 2)];
      u16x4 qv1 = *(const u16x4*)&QDs[qpb + s0 + 16 + (lhi << 2)];
      u16x4 kv0 = *(const u16x4*)&kdl[s0 + (lhi << 2)];
      u16x4 kv1 = *(const u16x4*)&kdl[s0 + 16 + (lhi << 2)];
#pragma unroll
      for (int r = 0; r < 4; ++r) {
        p[r]     = ex2(st0[r] + bf2f(qv0[r]) + bf2f(kv0[r]));
        p[4 + r] = ex2(st1[r] + bf2f(qv1[r]) + bf2f(kv1[r]));
      }
    } else {
      // boundary: vector loads + per-element clamped select
      u16x4 kv0 = *(const u16x4*)&kdl[s0 + (lhi << 2)];
      u16x4 kv1 = *(const u16x4*)&kdl[s0 + 16 + (lhi << 2)];
      u16x4 a00 = *(const u16x4*)&k0g[s0 + (lhi << 2)];
      u16x4 a01 = *(const u16x4*)&k0g[s0 + 16 + (lhi << 2)];
      u16x4 a20 = *(const u16x4*)&k2g[s0 + (lhi << 2)];
      u16x4 a21 = *(const u16x4*)&k2g[s0 + 16 + (lhi << 2)];
#pragma unroll
      for (int i = 0; i < 2; ++i)
#pragma unroll
        for (int r = 0; r < 4; ++r) {
          const int scol = s0 + i * 16 + (lhi << 2) + r;
          int j = scol - lg + 128;                 // = 256 - d
          int jc = j < 0 ? 0 : (j > 256 ? 256 : j);
          float qd = bf2f(QDs[qrb + jc]);
          u16 kin = i ? kv1[r] : kv0[r];
          u16 klo = i ? a01[r] : a00[r];
          u16 khi = i ? a21[r] : a20[r];
          u16 ksel = (j <= 0) ? khi : ((j >= 256) ? klo : kin);
          p[i * 4 + r] = ex2((i ? st1[r] : st0[r]) + qd + bf2f(ksel));
        }
    }
    lacc += ((p[0] + p[1]) + (p[2] + p[3])) + ((p[4] + p[5]) + (p[6] + p[7]));

    // pack P (bf16, trunc-round) into per-wave LDS, XOR-swizzled 8B units
#pragma unroll
    for (int i = 0; i < 2; ++i)
#pragma unroll
      for (int b = 0; b < 2; ++b) {
        union { float f; unsigned u; } a0, a1;
        a0.f = p[i * 4 + 2 * b]; a1.f = p[i * 4 + 2 * b + 1];
        unsigned wv = ((a0.u + 0x8000u) >> 16) | ((a1.u + 0x8000u) & 0xffff0000u);
        int u = (i * 4 + lhi) ^ (llo & 6);
        *reinterpret_cast<unsigned*>(Pw + llo * 64 + u * 8 + b * 4) = wv;
      }
    short8 pB = *reinterpret_cast<const short8*>(
        Pw + llo * 64 + (((lhi * 2) ^ (llo & 6)) * 8));
    short8 vA0 = *(const short8*)&vb[(size_t)llo * L_ + s0 + lhi * 8];
    short8 vA1 = *(const short8*)&vb[(size_t)(16 + llo) * L_ + s0 + lhi * 8];
    o0 = mfma16(vA0, pB, o0);
    o1 = mfma16(vA1, pB, o1);
  }

  // row sum across the 4 lanes sharing llo (lane, lane^16, lane^32, lane^48)
  float l2 = lacc + __shfl_xor(lacc, 16);
  float lt = l2 + __shfl_xor(l2, 32);
  const float inv = 1.0f / lt;

  const int n = nh >> 5, h = nh & 31;
  const size_t obase = (((size_t)((n << 10) | lg)) * 32 + h) * 32;
  u16x4 w0, w1;
#pragma unroll
  for (int r = 0; r < 4; ++r) {
    w0[r] = f2bf(o0[r] * inv);
    w1[r] = f2bf(o1[r] * inv);
  }
  *reinterpret_cast<u16x4*>(&tb[obase + lhi * 4]) = w0;        // e = lhi*4+r
  *reinterpret_cast<u16x4*>(&tb[obase + 16 + lhi * 4]) = w1;   // e = 16+lhi*4+r
}

// ---- AddNorm 1: h = LN(t + x) -> bf16 ----
__global__ __launch_bounds__(256) void ln1_kernel(
    const u16* __restrict__ tbuf, const float* __restrict__ x,
    const float* __restrict__ g, const float* __restrict__ b,
    u16* __restrict__ hb) {
  __shared__ float red[8];
  const int row = blockIdx.x, tid = threadIdx.x;
  const size_t base = (size_t)row * C_ + tid * 4;
  f32x4 xv = *reinterpret_cast<const f32x4*>(&x[base]);
  u16x4 tv = *reinterpret_cast<const u16x4*>(&tbuf[base]);
  float v[4]; float s1 = 0.f, s2 = 0.f;
#pragma unroll
  for (int i = 0; i < 4; ++i) {
    v[i] = xv[i] + bf2f(tv[i]);
    s1 += v[i]; s2 += v[i] * v[i];
  }
#pragma unroll
  for (int off = 32; off >= 1; off >>= 1) {
    s1 += __shfl_xor(s1, off); s2 += __shfl_xor(s2, off);
  }
  if ((tid & 63) == 0) { red[tid >> 6] = s1; red[4 + (tid >> 6)] = s2; }
  __syncthreads();
  float S1 = red[0] + red[1] + red[2] + red[3];
  float S2 = red[4] + red[5] + red[6] + red[7];
  float mu = S1 * (1.f / C_);
  float rs = rsqrtf(S2 * (1.f / C_) - mu * mu + 1e-5f);
#pragma unroll
  for (int i = 0; i < 4; ++i) {
    int c = tid * 4 + i;
    hb[base + i] = f2bf((v[i] - mu) * rs * g[c] + b[c]);
  }
}

// ---- AddNorm 2: out = LN(m + h) -> fp32, transposed (L, N, C) ----
__global__ __launch_bounds__(256) void ln2_kernel(
    const u16* __restrict__ mb, const u16* __restrict__ hb,
    const float* __restrict__ g, const float* __restrict__ b,
    float* __restrict__ out) {
  __shared__ float red[8];
  const int row = blockIdx.x, tid = threadIdx.x;
  const size_t base = (size_t)row * C_ + tid * 4;
  u16x4 mv = *reinterpret_cast<const u16x4*>(&mb[base]);
  u16x4 hv = *reinterpret_cast<const u16x4*>(&hb[base]);
  float v[4]; float s1 = 0.f, s2 = 0.f;
#pragma unroll
  for (int i = 0; i < 4; ++i) {
    v[i] = bf2f(mv[i]) + bf2f(hv[i]);
    s1 += v[i]; s2 += v[i] * v[i];
  }
#pragma unroll
  for (int off = 32; off >= 1; off >>= 1) {
    s1 += __shfl_xor(s1, off); s2 += __shfl_xor(s2, off);
  }
  if ((tid & 63) == 0) { red[tid >> 6] = s1; red[4 + (tid >> 6)] = s2; }
  __syncthreads();
  float S1 = red[0] + red[1] + red[2] + red[3];
  float S2 = red[4] + red[5] + red[6] + red[7];
  float mu = S1 * (1.f / C_);
  float rs = rsqrtf(S2 * (1.f / C_) - mu * mu + 1e-5f);
  const int n = row >> 10, l = row & 1023;
  const size_t ob = (size_t)(l * N_ + n) * C_ + tid * 4;
#pragma unroll
  for (int i = 0; i < 4; ++i) {
    int c = tid * 4 + i;
    out[ob + i] = (v[i] - mu) * rs * g[c] + b[c];
  }
}

extern "C" void kernel_launch(void* const* d_in, const int* in_sizes, int n_in,
                              void* d_out, int out_size, void* d_ws, size_t ws_size,
                              hipStream_t stream) {
  const float* x    = (const float*)d_in[0];
  const float* Wq   = (const float*)d_in[1];
  const float* bq   = (const float*)d_in[2];
  const float* Wk   = (const float*)d_in[3];
  const float* bk   = (const float*)d_in[4];
  const float* Wv   = (const float*)d_in[5];
  const float* bv   = (const float*)d_in[6];
  const float* demb = (const float*)d_in[7];
  const float* g1   = (const float*)d_in[8];
  const float* b1ln = (const float*)d_in[9];
  const float* g2   = (const float*)d_in[10];
  const float* b2ln = (const float*)d_in[11];
  const float* W1   = (const float*)d_in[12];
  const float* b1   = (const float*)d_in[13];
  const float* W2   = (const float*)d_in[14];
  const float* b2   = (const float*)d_in[15];
  float* outp = (float*)d_out;

  size_t o = 0;
  auto alloc = [&](size_t bytes) { size_t r = o; o += (bytes + 255) & ~(size_t)255; return r; };
  const size_t xb_o    = alloc((size_t)M_ * C_ * 2);
  const size_t wqkv_o  = alloc((size_t)3 * C_ * C_ * 2);   // contiguous with w1,w2
  const size_t w1_o    = alloc((size_t)C_ * C_ * 2);
  const size_t w2_o    = alloc((size_t)C_ * C_ * 2);
  const size_t bqkv_o  = alloc((size_t)3 * C_ * 4);
  const size_t demb_o  = alloc((size_t)DPAD * E_ * 2);
  const size_t q_o     = alloc((size_t)NH_ * L_ * E_ * 2);
  const size_t k_o     = alloc((size_t)NH_ * L_ * E_ * 2);
  const size_t vt_o    = alloc((size_t)NH_ * L_ * E_ * 2);
  const size_t kdb_o   = alloc((size_t)NH_ * L_ * D_ * 2);
  const size_t kd0_o   = alloc((size_t)NH_ * L_ * 2);
  const size_t kd256_o = alloc((size_t)NH_ * L_ * 2);
  const size_t t_o     = alloc((size_t)M_ * C_ * 2);
  const size_t h_o     = alloc((size_t)M_ * C_ * 2);
  const size_t m1_o    = alloc((size_t)M_ * C_ * 2);
  const size_t m_o     = alloc((size_t)M_ * C_ * 2);
  if (o > ws_size) return;  // ws too small -> visible zero-output failure

  char* ws = (char*)d_ws;
  u16*   xb     = (u16*)(ws + xb_o);
  u16*   wqkv_t = (u16*)(ws + wqkv_o);
  u16*   w1_t   = (u16*)(ws + w1_o);
  u16*   w2_t   = (u16*)(ws + w2_o);
  float* bqkv   = (float*)(ws + bqkv_o);
  u16*   demb_b = (u16*)(ws + demb_o);
  u16*   q_ws   = (u16*)(ws + q_o);
  u16*   k_ws   = (u16*)(ws + k_o);
  u16*   vT_ws  = (u16*)(ws + vt_o);
  u16*   kdb    = (u16*)(ws + kdb_o);
  u16*   kd0a   = (u16*)(ws + kd0_o);
  u16*   kd256a = (u16*)(ws + kd256_o);
  u16*   t_b16  = (u16*)(ws + t_o);
  u16*   h_b16  = (u16*)(ws + h_o);
  u16*   m1_b16 = (u16*)(ws + m1_o);
  u16*   m_b16  = (u16*)(ws + m_o);

  misc_kernel<<<4096 + 34, 256, 0, stream>>>(x, demb, bq, bk, bv, xb, demb_b, bqkv);
  dim3 tb_(32, 8), tg_(32, 32, 5);
  transpose_w_kernel<<<tg_, tb_, 0, stream>>>(Wq, Wk, Wv, W1, W2, wqkv_t);

  gemm128_kernel<0><<<32 * 24, 256, 0, stream>>>(xb, wqkv_t, C_, bqkv, q_ws, k_ws, vT_ws);

  qdkd_kernel<<<2048, 256, 0, stream>>>(k_ws, demb_b, kdb, kd0a, kd256a);

  attn_kernel<<<NH_ * 16, 256, 0, stream>>>(q_ws, k_ws, vT_ws, demb_b, kdb, kd0a, kd256a, t_b16);

  ln1_kernel<<<M_, 256, 0, stream>>>(t_b16, x, g1, b1ln, h_b16);

  gemm128_kernel<1><<<32 * 8, 256, 0, stream>>>(h_b16, w1_t, C_, b1, m1_b16, nullptr, nullptr);
  gemm128_kernel<2><<<32 * 8, 256, 0, stream>>>(m1_b16, w2_t, C_, b2, m_b16, nullptr, nullptr);

  ln2_kernel<<<M_, 256, 0, stream>>>(m_b16, h_b16, g2, b2ln, outp);
}

// Round 10
// 298.413 us; speedup vs baseline: 1.0859x; 1.0859x over previous
//
#include <hip/hip_runtime.h>

#define H_ 32
#define E_ 32
#define C_ 1024
#define L_ 1024
#define N_ 4
#define M_ 4096      // N_*L_
#define NH_ 128      // N_*H_
#define D_ 257
#define DPAD 272     // demb padded rows (zeros beyond 256)
#define TEMP_ 0.17677669529663687f
#define QSCALE_ (TEMP_ * 1.4426950408889634f)   // temp * log2(e), folded into q & KD

typedef unsigned short u16;
typedef __attribute__((ext_vector_type(8))) short short8;
typedef __attribute__((ext_vector_type(4))) float f32x4;
typedef __attribute__((ext_vector_type(4))) unsigned short u16x4;

__device__ __forceinline__ u16 f2bf(float f) {
  union { float f; unsigned u; } v; v.f = f;
  unsigned r = v.u + 0x7fffu + ((v.u >> 16) & 1u);
  return (u16)(r >> 16);
}
__device__ __forceinline__ float bf2f(u16 h) {
  union { unsigned u; float f; } v; v.u = ((unsigned)h) << 16;
  return v.f;
}
__device__ __forceinline__ f32x4 mfma16(short8 a, short8 b, f32x4 c) {
  return __builtin_amdgcn_mfma_f32_16x16x32_bf16(a, b, c, 0, 0, 0);
}
__device__ __forceinline__ float ex2(float x) {
#if __has_builtin(__builtin_amdgcn_exp2f)
  return __builtin_amdgcn_exp2f(x);
#else
  float r;
  asm("v_exp_f32 %0, %1\n\ts_nop 1" : "=v"(r) : "v"(x));
  return r;
#endif
}
// async global->LDS, 16B per lane; lds base must be wave-uniform
__device__ __forceinline__ void gld16(const u16* g, u16* l) {
  __builtin_amdgcn_global_load_lds(
      (const __attribute__((address_space(1))) unsigned int*)g,
      (__attribute__((address_space(3))) unsigned int*)l, 16, 0, 0);
}

// ---- misc: x->bf16 conversion + dist_emb->bf16 (padded) + qkv bias pack ----
__global__ __launch_bounds__(256) void misc_kernel(
    const float* __restrict__ x, const float* __restrict__ demb,
    const float* __restrict__ bq, const float* __restrict__ bk,
    const float* __restrict__ bv, u16* __restrict__ xb,
    u16* __restrict__ demb_b, float* __restrict__ bqkv) {
  const int b = blockIdx.x, tid = threadIdx.x;
  if (b < 4096) {
    int i = b * 256 + tid;
    f32x4 v = reinterpret_cast<const f32x4*>(x)[i];
    u16x4 o2;
    o2[0] = f2bf(v[0]); o2[1] = f2bf(v[1]); o2[2] = f2bf(v[2]); o2[3] = f2bf(v[3]);
    reinterpret_cast<u16x4*>(xb)[i] = o2;
  } else {
    int i = (b - 4096) * 256 + tid;
    if (i < DPAD * E_) demb_b[i] = (i < D_ * E_) ? f2bf(demb[i]) : (u16)0;
    if (i < C_) { bqkv[i] = bq[i]; bqkv[C_ + i] = bk[i]; bqkv[2 * C_ + i] = bv[i]; }
  }
}

// ---- 5 weight transposes in one launch: W (K x N) -> W^T (N x K) bf16 ----
__global__ __launch_bounds__(256) void transpose_w_kernel(
    const float* __restrict__ Wq, const float* __restrict__ Wk,
    const float* __restrict__ Wv, const float* __restrict__ W1,
    const float* __restrict__ W2, u16* __restrict__ out_base) {
  __shared__ float tile[32][33];
  const int z = blockIdx.z;
  const float* in = (z == 0) ? Wq : (z == 1) ? Wk : (z == 2) ? Wv : (z == 3) ? W1 : W2;
  u16* out = out_base + (size_t)z * C_ * C_;
  int j0 = blockIdx.x * 32, c0 = blockIdx.y * 32;
#pragma unroll
  for (int i = 0; i < 4; ++i) {
    int cy = threadIdx.y + i * 8;
    tile[cy][threadIdx.x] = in[(size_t)(c0 + cy) * C_ + j0 + threadIdx.x];
  }
  __syncthreads();
#pragma unroll
  for (int i = 0; i < 4; ++i) {
    int jy = threadIdx.y + i * 8;
    out[(size_t)(j0 + jy) * C_ + c0 + threadIdx.x] = f2bf(tile[threadIdx.x][jy]);
  }
}

// ---- GEMM: C[M x Ncols] = A[M x K] * Bt[Ncols x K]^T, bf16 in / fp32 acc ----
template <int EPI>
__global__ __launch_bounds__(256) void gemm128_kernel(
    const u16* __restrict__ A, const u16* __restrict__ Bt, int K,
    const float* __restrict__ bias,
    u16* __restrict__ out0, u16* __restrict__ out1, u16* __restrict__ out2) {
  __shared__ u16 As[128 * 64];
  __shared__ u16 Bs[128 * 64];
  const int bid = blockIdx.x;
  const int m0 = (bid & 31) << 7;
  const int n0 = (bid >> 5) << 7;
  const int tid = threadIdx.x;
  const int w = tid >> 6, lane = tid & 63, lhi = lane >> 4, llo = lane & 15;
  const int wr = w >> 1, wc = w & 1;
  const int w4 = w << 2;
  const int srow = lane >> 3, scol = (lane & 7) << 3;
  f32x4 acc[4][4] = {};
  for (int k0 = 0; k0 < K; k0 += 64) {
#pragma unroll
    for (int j = 0; j < 4; ++j) {
      const int seg = w4 + j;
      const int row = (seg << 3) + srow;
      gld16(&A[(size_t)(m0 + row) * K + k0 + scol], &As[seg << 9]);
      gld16(&Bt[(size_t)(n0 + row) * K + k0 + scol], &Bs[seg << 9]);
    }
    __syncthreads();
#pragma unroll
    for (int kk = 0; kk < 2; ++kk) {
      const int ko = (kk << 5) + lhi * 8;
      short8 af[4], bf[4];
#pragma unroll
      for (int mi = 0; mi < 4; ++mi)
        af[mi] = *reinterpret_cast<const short8*>(&As[(wr * 64 + mi * 16 + llo) * 64 + ko]);
#pragma unroll
      for (int ni = 0; ni < 4; ++ni)
        bf[ni] = *reinterpret_cast<const short8*>(&Bs[(wc * 64 + ni * 16 + llo) * 64 + ko]);
#pragma unroll
      for (int mi = 0; mi < 4; ++mi)
#pragma unroll
        for (int ni = 0; ni < 4; ++ni)
          acc[mi][ni] = mfma16(af[mi], bf[ni], acc[mi][ni]);
    }
    __syncthreads();
  }
#pragma unroll
  for (int mi = 0; mi < 4; ++mi)
#pragma unroll
    for (int ni = 0; ni < 4; ++ni)
#pragma unroll
      for (int r = 0; r < 4; ++r) {
        int row = m0 + wr * 64 + mi * 16 + lhi * 4 + r;
        int col = n0 + wc * 64 + ni * 16 + llo;
        float v = acc[mi][ni][r] + bias[col];
        if constexpr (EPI == 0) {
          int which = col >> 10, jj = col & 1023, h = jj >> 5, e2 = jj & 31;
          int n = row >> 10, l = row & 1023;
          int nh = (n << 5) | h;
          if (which == 0) v *= QSCALE_;   // fold temp*log2e into q
          u16 bvv = f2bf(v);
          if (which == 0)      out0[((size_t)((nh << 10) | l)) * 32 + e2] = bvv;
          else if (which == 1) out1[((size_t)((nh << 10) | l)) * 32 + e2] = bvv;
          else                 out2[(((size_t)(nh * 32 + e2)) << 10) | l] = bvv;
        } else if constexpr (EPI == 1) {
          out0[(size_t)row * C_ + col] = f2bf(fmaxf(v, 0.f));
        } else {
          out0[(size_t)row * C_ + col] = f2bf(v);
        }
      }
}

// ---- KD: dst[m, d] = QSCALE * sum_e k[m, e] * demb[d, e]; aux clamp vecs ----
// (R7 version: coalesced row-major writes.)
__global__ __launch_bounds__(256) void qdkd_kernel(
    const u16* __restrict__ src, const u16* __restrict__ demb,
    u16* __restrict__ dst, u16* __restrict__ aux0, u16* __restrict__ aux256) {
  const int wt = blockIdx.x * 4 + (threadIdx.x >> 6);
  const int lane = threadIdx.x & 63, lhi = lane >> 4, llo = lane & 15;
  const int m0 = wt << 4;
  short8 a = *reinterpret_cast<const short8*>(&src[(size_t)(m0 + llo) * E_ + lhi * 8]);
#pragma unroll
  for (int ct = 0; ct < 17; ++ct) {
    int d = ct * 16 + llo;
    short8 b = *reinterpret_cast<const short8*>(&demb[d * E_ + lhi * 8]);
    f32x4 c = {};
    c = mfma16(a, b, c);
    if (d < D_) {
#pragma unroll
      for (int r = 0; r < 4; ++r) {
        u16 val = f2bf(c[r] * QSCALE_);
        dst[(size_t)(m0 + lhi * 4 + r) * D_ + d] = val;
        if (d == 0)   aux0[m0 + lhi * 4 + r] = val;
        if (d == 256) aux256[m0 + lhi * 4 + r] = val;
      }
    }
  }
}

// ---- attention v10: swapped orientation on R7's simple loop ----
// mfma(Q, K): lane holds S[q = lw0 + lhi*4 + r][s]. Even/odd s interleave:
// st0 -> s = s0 + 2*llo, st1 -> s = s0 + 2*llo + 1 (P pair packs as one b32).
// In-band KD reads are CONTIGUOUS u16x4 from the coalesced KD[s][d] array
// (flat = 256*s + q + 128, +1 per r). QD table stride 257 (cols 0..256),
// scalar reads dense in llo (conflict-free). No barriers; LDS 38272 B
// -> 4 blocks/CU.
__global__ __launch_bounds__(256, 4) void attn_kernel(
    const u16* __restrict__ qw, const u16* __restrict__ kw,
    const u16* __restrict__ vT, const u16* __restrict__ dembp,
    const u16* __restrict__ KDg, const u16* __restrict__ kd0a,
    const u16* __restrict__ kd256a, u16* __restrict__ tb) {
  __shared__ u16 QDs[64 * 257];     // 32896 B, wave-local (q-local row * 257 + d)
  __shared__ u16 Pbuf[4 * 16 * 40]; // 5120 B: per-wave P[q16][s32] stride 40
  __shared__ float Lred[64];
  const int bid = blockIdx.x;
  const int nh = bid & (NH_ - 1);     // XCD-friendly
  const int l0 = (bid >> 7) << 6;
  const int tid = threadIdx.x;
  const int w = tid >> 6, lane = tid & 63, lhi = lane >> 4, llo = lane & 15;
  const int lw0 = l0 + (w << 4);
  const int lg = lw0 + llo;

  const u16* qb  = qw + (size_t)nh * (L_ * E_);
  const u16* kb  = kw + (size_t)nh * (L_ * E_);
  const u16* vb  = vT + (size_t)nh * (E_ * L_);
  const u16* kdg = KDg + (size_t)nh * ((size_t)L_ * D_);
  const u16* k0g = kd0a + (size_t)nh * L_;
  const u16* k2g = kd256a + (size_t)nh * L_;

  // q fragment: lane holds q[lg][lhi*8..+8) (A-operand rows = llo)
  const short8 qA = *(const short8*)&qb[(size_t)lg * E_ + lhi * 8];
  const int qr4 = (w << 4) + (lhi << 2);   // q-local base for this lane's rows

  // build QD table (stride 257): QDs[q_local][d] = q[q]·demb[d]
#pragma unroll
  for (int dt = 0; dt < 17; ++dt) {
    const int col = dt * 16 + llo;
    short8 db = *(const short8*)&dembp[col * E_ + lhi * 8];   // col < 272, padded
    f32x4 qd = {};
    qd = mfma16(qA, db, qd);
    if (col < 257) {
#pragma unroll
      for (int r = 0; r < 4; ++r)
        QDs[(qr4 + r) * 257 + col] = f2bf(qd[r]);
    }
  }
  float qdf0[4], qdf256[4];
#pragma unroll
  for (int r = 0; r < 4; ++r) {
    qdf0[r]   = bf2f(QDs[(qr4 + r) * 257 + 0]);
    qdf256[r] = bf2f(QDs[(qr4 + r) * 257 + 256]);
  }

  f32x4 o0 = {}, o1 = {};
  float lacc[4] = {0.f, 0.f, 0.f, 0.f};
  u16* Pw = &Pbuf[w * 16 * 40];

  for (int s0 = 0; s0 < L_; s0 += 32) {
    const int se = s0 + 2 * llo;   // this lane's even s; odd is se+1
    short8 kB0 = *(const short8*)&kb[(size_t)se * E_ + lhi * 8];
    short8 kB1 = *(const short8*)&kb[(size_t)(se + 1) * E_ + lhi * 8];
    f32x4 st0 = {}, st1 = {};
    st0 = mfma16(qA, kB0, st0);   // D[row=q (lhi*4+r)][col=s (llo slot)]
    st1 = mfma16(qA, kB1, st1);

    float p0[4], p1[4];
    const int delta = lw0 - s0;
    if (delta >= 159 || delta <= -143) {
      // far: fully clamped. kc r-invariant (one u32 = both s values).
      const bool fh = delta >= 159;
      const float* qdf = fh ? qdf256 : qdf0;
      const u16* kcg = fh ? k2g : k0g;
      unsigned kc2 = *(const unsigned*)&kcg[se];
      const float kf0 = bf2f((u16)kc2), kf1 = bf2f((u16)(kc2 >> 16));
#pragma unroll
      for (int r = 0; r < 4; ++r) {
        p0[r] = ex2(st0[r] + qdf[r] + kf0);
        p1[r] = ex2(st1[r] + qdf[r] + kf1);
      }
    } else if (delta >= -97 && delta <= 113) {
      // pure in-band: KD contiguous u16x4 (flat = 256*s + q + 128), QD scalar
      const int fb = (se << 8) + lw0 + (lhi << 2) + 128;
      u16x4 kv0 = *(const u16x4*)&kdg[fb];
      u16x4 kv1 = *(const u16x4*)&kdg[fb + 256];
      const int dq = lw0 + (lhi << 2) - se + 128;   // d for r=0 (st0)
#pragma unroll
      for (int r = 0; r < 4; ++r) {
        float qd0 = bf2f(QDs[(qr4 + r) * 257 + dq + r]);
        float qd1 = bf2f(QDs[(qr4 + r) * 257 + dq + r - 1]);
        p0[r] = ex2(st0[r] + qd0 + bf2f(kv0[r]));
        p1[r] = ex2(st1[r] + qd1 + bf2f(kv1[r]));
      }
    } else {
      // boundary: clamped d indexes the real KD row (cols 0/256 hold clamps)
      const int rb0 = se * D_, rb1 = rb0 + D_;
#pragma unroll
      for (int r = 0; r < 4; ++r) {
        const int q = lw0 + (lhi << 2) + r;
        int d0 = q - se + 128;
        d0 = d0 < 0 ? 0 : (d0 > 256 ? 256 : d0);
        int d1 = q - se + 127;
        d1 = d1 < 0 ? 0 : (d1 > 256 ? 256 : d1);
        float qd0 = bf2f(QDs[(qr4 + r) * 257 + d0]);
        float qd1 = bf2f(QDs[(qr4 + r) * 257 + d1]);
        p0[r] = ex2(st0[r] + qd0 + bf2f(kdg[rb0 + d0]));
        p1[r] = ex2(st1[r] + qd1 + bf2f(kdg[rb1 + d1]));
      }
    }

    // denominator + pack P pairs (s = 2llo, 2llo+1) as one b32 per q-row
#pragma unroll
    for (int r = 0; r < 4; ++r) {
      lacc[r] += p0[r] + p1[r];
      union { float f; unsigned u; } a0, a1;
      a0.f = p0[r]; a1.f = p1[r];
      unsigned pw = ((a0.u + 0x8000u) >> 16) | ((a1.u + 0x8000u) & 0xffff0000u);
      *reinterpret_cast<unsigned*>(&Pw[((lhi << 2) + r) * 40 + 2 * llo]) = pw;
    }
    // PV: B-operand rows = q (llo slot), k-slice = s0 + lhi*8..+8
    short8 pB = *(const short8*)&Pw[llo * 40 + lhi * 8];
    short8 vA0 = *(const short8*)&vb[(size_t)llo * L_ + s0 + lhi * 8];
    short8 vA1 = *(const short8*)&vb[(size_t)(16 + llo) * L_ + s0 + lhi * 8];
    o0 = mfma16(vA0, pB, o0);   // D[row=e][col=q]
    o1 = mfma16(vA1, pB, o1);
  }

  // denominator: reduce over the 16 llo lanes, redistribute via LDS
#pragma unroll
  for (int r = 0; r < 4; ++r) {
    float t = lacc[r];
    t += __shfl_xor(t, 1); t += __shfl_xor(t, 2);
    t += __shfl_xor(t, 4); t += __shfl_xor(t, 8);
    if (llo == 0) Lred[(w << 4) + (lhi << 2) + r] = t;
  }
  const float inv = 1.0f / Lred[(w << 4) + llo];   // same-wave LDS

  const int n = nh >> 5, h = nh & 31;
  const size_t obase = (((size_t)((n << 10) | lg)) * 32 + h) * 32;
  u16x4 w0, w1;
#pragma unroll
  for (int r = 0; r < 4; ++r) {
    w0[r] = f2bf(o0[r] * inv);
    w1[r] = f2bf(o1[r] * inv);
  }
  *reinterpret_cast<u16x4*>(&tb[obase + (lhi << 2)]) = w0;        // e = lhi*4+r
  *reinterpret_cast<u16x4*>(&tb[obase + 16 + (lhi << 2)]) = w1;   // e = 16+lhi*4+r
}

// ---- AddNorm 1: h = LN(t + x) -> bf16 ----
__global__ __launch_bounds__(256) void ln1_kernel(
    const u16* __restrict__ tbuf, const float* __restrict__ x,
    const float* __restrict__ g, const float* __restrict__ b,
    u16* __restrict__ hb) {
  __shared__ float red[8];
  const int row = blockIdx.x, tid = threadIdx.x;
  const size_t base = (size_t)row * C_ + tid * 4;
  f32x4 xv = *reinterpret_cast<const f32x4*>(&x[base]);
  u16x4 tv = *reinterpret_cast<const u16x4*>(&tbuf[base]);
  float v[4]; float s1 = 0.f, s2 = 0.f;
#pragma unroll
  for (int i = 0; i < 4; ++i) {
    v[i] = xv[i] + bf2f(tv[i]);
    s1 += v[i]; s2 += v[i] * v[i];
  }
#pragma unroll
  for (int off = 32; off >= 1; off >>= 1) {
    s1 += __shfl_xor(s1, off); s2 += __shfl_xor(s2, off);
  }
  if ((tid & 63) == 0) { red[tid >> 6] = s1; red[4 + (tid >> 6)] = s2; }
  __syncthreads();
  float S1 = red[0] + red[1] + red[2] + red[3];
  float S2 = red[4] + red[5] + red[6] + red[7];
  float mu = S1 * (1.f / C_);
  float rs = rsqrtf(S2 * (1.f / C_) - mu * mu + 1e-5f);
#pragma unroll
  for (int i = 0; i < 4; ++i) {
    int c = tid * 4 + i;
    hb[base + i] = f2bf((v[i] - mu) * rs * g[c] + b[c]);
  }
}

// ---- AddNorm 2: out = LN(m + h) -> fp32, transposed (L, N, C) ----
__global__ __launch_bounds__(256) void ln2_kernel(
    const u16* __restrict__ mb, const u16* __restrict__ hb,
    const float* __restrict__ g, const float* __restrict__ b,
    float* __restrict__ out) {
  __shared__ float red[8];
  const int row = blockIdx.x, tid = threadIdx.x;
  const size_t base = (size_t)row * C_ + tid * 4;
  u16x4 mv = *reinterpret_cast<const u16x4*>(&mb[base]);
  u16x4 hv = *reinterpret_cast<const u16x4*>(&hb[base]);
  float v[4]; float s1 = 0.f, s2 = 0.f;
#pragma unroll
  for (int i = 0; i < 4; ++i) {
    v[i] = bf2f(mv[i]) + bf2f(hv[i]);
    s1 += v[i]; s2 += v[i] * v[i];
  }
#pragma unroll
  for (int off = 32; off >= 1; off >>= 1) {
    s1 += __shfl_xor(s1, off); s2 += __shfl_xor(s2, off);
  }
  if ((tid & 63) == 0) { red[tid >> 6] = s1; red[4 + (tid >> 6)] = s2; }
  __syncthreads();
  float S1 = red[0] + red[1] + red[2] + red[3];
  float S2 = red[4] + red[5] + red[6] + red[7];
  float mu = S1 * (1.f / C_);
  float rs = rsqrtf(S2 * (1.f / C_) - mu * mu + 1e-5f);
  const int n = row >> 10, l = row & 1023;
  const size_t ob = (size_t)(l * N_ + n) * C_ + tid * 4;
#pragma unroll
  for (int i = 0; i < 4; ++i) {
    int c = tid * 4 + i;
    out[ob + i] = (v[i] - mu) * rs * g[c] + b[c];
  }
}

extern "C" void kernel_launch(void* const* d_in, const int* in_sizes, int n_in,
                              void* d_out, int out_size, void* d_ws, size_t ws_size,
                              hipStream_t stream) {
  const float* x    = (const float*)d_in[0];
  const float* Wq   = (const float*)d_in[1];
  const float* bq   = (const float*)d_in[2];
  const float* Wk   = (const float*)d_in[3];
  const float* bk   = (const float*)d_in[4];
  const float* Wv   = (const float*)d_in[5];
  const float* bv   = (const float*)d_in[6];
  const float* demb = (const float*)d_in[7];
  const float* g1   = (const float*)d_in[8];
  const float* b1ln = (const float*)d_in[9];
  const float* g2   = (const float*)d_in[10];
  const float* b2ln = (const float*)d_in[11];
  const float* W1   = (const float*)d_in[12];
  const float* b1   = (const float*)d_in[13];
  const float* W2   = (const float*)d_in[14];
  const float* b2   = (const float*)d_in[15];
  float* outp = (float*)d_out;

  size_t o = 0;
  auto alloc = [&](size_t bytes) { size_t r = o; o += (bytes + 255) & ~(size_t)255; return r; };
  const size_t xb_o    = alloc((size_t)M_ * C_ * 2);
  const size_t wqkv_o  = alloc((size_t)3 * C_ * C_ * 2);   // contiguous with w1,w2
  const size_t w1_o    = alloc((size_t)C_ * C_ * 2);
  const size_t w2_o    = alloc((size_t)C_ * C_ * 2);
  const size_t bqkv_o  = alloc((size_t)3 * C_ * 4);
  const size_t demb_o  = alloc((size_t)DPAD * E_ * 2);
  const size_t q_o     = alloc((size_t)NH_ * L_ * E_ * 2);
  const size_t k_o     = alloc((size_t)NH_ * L_ * E_ * 2);
  const size_t vt_o    = alloc((size_t)NH_ * L_ * E_ * 2);
  const size_t kd_o    = alloc((size_t)NH_ * L_ * D_ * 2);
  const size_t kd0_o   = alloc((size_t)NH_ * L_ * 2);
  const size_t kd256_o = alloc((size_t)NH_ * L_ * 2);
  const size_t t_o     = alloc((size_t)M_ * C_ * 2);
  const size_t h_o     = alloc((size_t)M_ * C_ * 2);
  const size_t m1_o    = alloc((size_t)M_ * C_ * 2);
  const size_t m_o     = alloc((size_t)M_ * C_ * 2);
  if (o > ws_size) return;  // ws too small -> visible zero-output failure

  char* ws = (char*)d_ws;
  u16*   xb     = (u16*)(ws + xb_o);
  u16*   wqkv_t = (u16*)(ws + wqkv_o);
  u16*   w1_t   = (u16*)(ws + w1_o);
  u16*   w2_t   = (u16*)(ws + w2_o);
  float* bqkv   = (float*)(ws + bqkv_o);
  u16*   demb_b = (u16*)(ws + demb_o);
  u16*   q_ws   = (u16*)(ws + q_o);
  u16*   k_ws   = (u16*)(ws + k_o);
  u16*   vT_ws  = (u16*)(ws + vt_o);
  u16*   KD     = (u16*)(ws + kd_o);
  u16*   kd0a   = (u16*)(ws + kd0_o);
  u16*   kd256a = (u16*)(ws + kd256_o);
  u16*   t_b16  = (u16*)(ws + t_o);
  u16*   h_b16  = (u16*)(ws + h_o);
  u16*   m1_b16 = (u16*)(ws + m1_o);
  u16*   m_b16  = (u16*)(ws + m_o);

  misc_kernel<<<4096 + 34, 256, 0, stream>>>(x, demb, bq, bk, bv, xb, demb_b, bqkv);
  dim3 tb_(32, 8), tg_(32, 32, 5);
  transpose_w_kernel<<<tg_, tb_, 0, stream>>>(Wq, Wk, Wv, W1, W2, wqkv_t);

  gemm128_kernel<0><<<32 * 24, 256, 0, stream>>>(xb, wqkv_t, C_, bqkv, q_ws, k_ws, vT_ws);

  qdkd_kernel<<<2048, 256, 0, stream>>>(k_ws, demb_b, KD, kd0a, kd256a);

  attn_kernel<<<NH_ * 16, 256, 0, stream>>>(q_ws, k_ws, vT_ws, demb_b, KD, kd0a, kd256a, t_b16);

  ln1_kernel<<<M_, 256, 0, stream>>>(t_b16, x, g1, b1ln, h_b16);

  gemm128_kernel<1><<<32 * 8, 256, 0, stream>>>(h_b16, w1_t, C_, b1, m1_b16, nullptr, nullptr);
  gemm128_kernel<2><<<32 * 8, 256, 0, stream>>>(m1_b16, w2_t, C_, b2, m_b16, nullptr, nullptr);

  ln2_kernel<<<M_, 256, 0, stream>>>(m_b16, h_b16, g2, b2ln, outp);
}

// Round 11
// 264.719 us; speedup vs baseline: 1.2241x; 1.1273x over previous
//
#include <hip/hip_runtime.h>

#define H_ 32
#define E_ 32
#define C_ 1024
#define L_ 1024
#define N_ 4
#define M_ 4096      // N_*L_
#define NH_ 128      // N_*H_
#define D_ 257
#define DPAD 272     // demb padded rows (zeros beyond 256)
#define QDS 256      // QD row stride in LDS (col 256 lives in a register)
#define TEMP_ 0.17677669529663687f
#define QSCALE_ (TEMP_ * 1.4426950408889634f)   // temp * log2(e), folded into q & KD

typedef unsigned short u16;
typedef __attribute__((ext_vector_type(8))) short short8;
typedef __attribute__((ext_vector_type(4))) float f32x4;
typedef __attribute__((ext_vector_type(4))) unsigned short u16x4;

__device__ __forceinline__ u16 f2bf(float f) {
  union { float f; unsigned u; } v; v.f = f;
  unsigned r = v.u + 0x7fffu + ((v.u >> 16) & 1u);
  return (u16)(r >> 16);
}
__device__ __forceinline__ float bf2f(u16 h) {
  union { unsigned u; float f; } v; v.u = ((unsigned)h) << 16;
  return v.f;
}
__device__ __forceinline__ f32x4 mfma16(short8 a, short8 b, f32x4 c) {
  return __builtin_amdgcn_mfma_f32_16x16x32_bf16(a, b, c, 0, 0, 0);
}
__device__ __forceinline__ float ex2(float x) {
#if __has_builtin(__builtin_amdgcn_exp2f)
  return __builtin_amdgcn_exp2f(x);
#else
  float r;
  asm("v_exp_f32 %0, %1\n\ts_nop 1" : "=v"(r) : "v"(x));
  return r;
#endif
}
// async global->LDS, 16B per lane; lds base must be wave-uniform
__device__ __forceinline__ void gld16(const u16* g, u16* l) {
  __builtin_amdgcn_global_load_lds(
      (const __attribute__((address_space(1))) unsigned int*)g,
      (__attribute__((address_space(3))) unsigned int*)l, 16, 0, 0);
}

// ---- misc: x->bf16 conversion + dist_emb->bf16 (padded) + qkv bias pack ----
__global__ __launch_bounds__(256) void misc_kernel(
    const float* __restrict__ x, const float* __restrict__ demb,
    const float* __restrict__ bq, const float* __restrict__ bk,
    const float* __restrict__ bv, u16* __restrict__ xb,
    u16* __restrict__ demb_b, float* __restrict__ bqkv) {
  const int b = blockIdx.x, tid = threadIdx.x;
  if (b < 4096) {
    int i = b * 256 + tid;
    f32x4 v = reinterpret_cast<const f32x4*>(x)[i];
    u16x4 o2;
    o2[0] = f2bf(v[0]); o2[1] = f2bf(v[1]); o2[2] = f2bf(v[2]); o2[3] = f2bf(v[3]);
    reinterpret_cast<u16x4*>(xb)[i] = o2;
  } else {
    int i = (b - 4096) * 256 + tid;
    if (i < DPAD * E_) demb_b[i] = (i < D_ * E_) ? f2bf(demb[i]) : (u16)0;
    if (i < C_) { bqkv[i] = bq[i]; bqkv[C_ + i] = bk[i]; bqkv[2 * C_ + i] = bv[i]; }
  }
}

// ---- 5 weight transposes in one launch: W (K x N) -> W^T (N x K) bf16 ----
__global__ __launch_bounds__(256) void transpose_w_kernel(
    const float* __restrict__ Wq, const float* __restrict__ Wk,
    const float* __restrict__ Wv, const float* __restrict__ W1,
    const float* __restrict__ W2, u16* __restrict__ out_base) {
  __shared__ float tile[32][33];
  const int z = blockIdx.z;
  const float* in = (z == 0) ? Wq : (z == 1) ? Wk : (z == 2) ? Wv : (z == 3) ? W1 : W2;
  u16* out = out_base + (size_t)z * C_ * C_;
  int j0 = blockIdx.x * 32, c0 = blockIdx.y * 32;
#pragma unroll
  for (int i = 0; i < 4; ++i) {
    int cy = threadIdx.y + i * 8;
    tile[cy][threadIdx.x] = in[(size_t)(c0 + cy) * C_ + j0 + threadIdx.x];
  }
  __syncthreads();
#pragma unroll
  for (int i = 0; i < 4; ++i) {
    int jy = threadIdx.y + i * 8;
    out[(size_t)(j0 + jy) * C_ + c0 + threadIdx.x] = f2bf(tile[threadIdx.x][jy]);
  }
}

// ---- GEMM 128x128: C = A * Bt^T, bf16 in / fp32 acc (qkv projection) ----
template <int EPI>
__global__ __launch_bounds__(256) void gemm128_kernel(
    const u16* __restrict__ A, const u16* __restrict__ Bt, int K,
    const float* __restrict__ bias,
    u16* __restrict__ out0, u16* __restrict__ out1, u16* __restrict__ out2) {
  __shared__ u16 As[128 * 64];
  __shared__ u16 Bs[128 * 64];
  const int bid = blockIdx.x;
  const int m0 = (bid & 31) << 7;
  const int n0 = (bid >> 5) << 7;
  const int tid = threadIdx.x;
  const int w = tid >> 6, lane = tid & 63, lhi = lane >> 4, llo = lane & 15;
  const int wr = w >> 1, wc = w & 1;
  const int w4 = w << 2;
  const int srow = lane >> 3, scol = (lane & 7) << 3;
  f32x4 acc[4][4] = {};
  for (int k0 = 0; k0 < K; k0 += 64) {
#pragma unroll
    for (int j = 0; j < 4; ++j) {
      const int seg = w4 + j;
      const int row = (seg << 3) + srow;
      gld16(&A[(size_t)(m0 + row) * K + k0 + scol], &As[seg << 9]);
      gld16(&Bt[(size_t)(n0 + row) * K + k0 + scol], &Bs[seg << 9]);
    }
    __syncthreads();
#pragma unroll
    for (int kk = 0; kk < 2; ++kk) {
      const int ko = (kk << 5) + lhi * 8;
      short8 af[4], bf[4];
#pragma unroll
      for (int mi = 0; mi < 4; ++mi)
        af[mi] = *reinterpret_cast<const short8*>(&As[(wr * 64 + mi * 16 + llo) * 64 + ko]);
#pragma unroll
      for (int ni = 0; ni < 4; ++ni)
        bf[ni] = *reinterpret_cast<const short8*>(&Bs[(wc * 64 + ni * 16 + llo) * 64 + ko]);
#pragma unroll
      for (int mi = 0; mi < 4; ++mi)
#pragma unroll
        for (int ni = 0; ni < 4; ++ni)
          acc[mi][ni] = mfma16(af[mi], bf[ni], acc[mi][ni]);
    }
    __syncthreads();
  }
#pragma unroll
  for (int mi = 0; mi < 4; ++mi)
#pragma unroll
    for (int ni = 0; ni < 4; ++ni)
#pragma unroll
      for (int r = 0; r < 4; ++r) {
        int row = m0 + wr * 64 + mi * 16 + lhi * 4 + r;
        int col = n0 + wc * 64 + ni * 16 + llo;
        float v = acc[mi][ni][r] + bias[col];
        if constexpr (EPI == 0) {
          int which = col >> 10, jj = col & 1023, h = jj >> 5, e2 = jj & 31;
          int n = row >> 10, l = row & 1023;
          int nh = (n << 5) | h;
          if (which == 0) v *= QSCALE_;   // fold temp*log2e into q
          u16 bvv = f2bf(v);
          if (which == 0)      out0[((size_t)((nh << 10) | l)) * 32 + e2] = bvv;
          else if (which == 1) out1[((size_t)((nh << 10) | l)) * 32 + e2] = bvv;
          else                 out2[(((size_t)(nh * 32 + e2)) << 10) | l] = bvv;
        } else if constexpr (EPI == 1) {
          out0[(size_t)row * C_ + col] = f2bf(fmaxf(v, 0.f));
        } else {
          out0[(size_t)row * C_ + col] = f2bf(v);
        }
      }
}

// ---- GEMM 64x128 (MLP): 512 blocks -> 2 blocks/CU (occupancy fix) ----
// EPI 1: +bias, relu; EPI 2: +bias. Same staging/fragment pattern as gemm128.
template <int EPI>
__global__ __launch_bounds__(256, 4) void gemm64_kernel(
    const u16* __restrict__ A, const u16* __restrict__ Bt, int K,
    const float* __restrict__ bias, u16* __restrict__ out0) {
  __shared__ u16 As[64 * 64];     // 8192 B
  __shared__ u16 Bs[128 * 64];    // 16384 B
  const int bid = blockIdx.x;
  const int m0 = (bid & 63) << 6;
  const int n0 = (bid >> 6) << 7;
  const int tid = threadIdx.x;
  const int w = tid >> 6, lane = tid & 63, lhi = lane >> 4, llo = lane & 15;
  const int wr = w >> 1, wc = w & 1;   // wr: 32-row half, wc: 64-col half
  const int srow = lane >> 3, scol = (lane & 7) << 3;
  f32x4 acc[2][4] = {};
  for (int k0 = 0; k0 < K; k0 += 64) {
#pragma unroll
    for (int j = 0; j < 2; ++j) {       // A: 8 segs of 8 rows
      const int seg = w * 2 + j;
      const int row = (seg << 3) + srow;
      gld16(&A[(size_t)(m0 + row) * K + k0 + scol], &As[seg << 9]);
    }
#pragma unroll
    for (int j = 0; j < 4; ++j) {       // B: 16 segs of 8 rows
      const int seg = w * 4 + j;
      const int row = (seg << 3) + srow;
      gld16(&Bt[(size_t)(n0 + row) * K + k0 + scol], &Bs[seg << 9]);
    }
    __syncthreads();
#pragma unroll
    for (int kk = 0; kk < 2; ++kk) {
      const int ko = (kk << 5) + lhi * 8;
      short8 af[2], bf[4];
#pragma unroll
      for (int mi = 0; mi < 2; ++mi)
        af[mi] = *reinterpret_cast<const short8*>(&As[(wr * 32 + mi * 16 + llo) * 64 + ko]);
#pragma unroll
      for (int ni = 0; ni < 4; ++ni)
        bf[ni] = *reinterpret_cast<const short8*>(&Bs[(wc * 64 + ni * 16 + llo) * 64 + ko]);
#pragma unroll
      for (int mi = 0; mi < 2; ++mi)
#pragma unroll
        for (int ni = 0; ni < 4; ++ni)
          acc[mi][ni] = mfma16(af[mi], bf[ni], acc[mi][ni]);
    }
    __syncthreads();
  }
#pragma unroll
  for (int mi = 0; mi < 2; ++mi)
#pragma unroll
    for (int ni = 0; ni < 4; ++ni)
#pragma unroll
      for (int r = 0; r < 4; ++r) {
        int row = m0 + wr * 32 + mi * 16 + lhi * 4 + r;
        int col = n0 + wc * 64 + ni * 16 + llo;
        float v = acc[mi][ni][r] + bias[col];
        if constexpr (EPI == 1) out0[(size_t)row * C_ + col] = f2bf(fmaxf(v, 0.f));
        else                    out0[(size_t)row * C_ + col] = f2bf(v);
      }
}

// ---- KD: dst[m, d] = QSCALE * sum_e k[m, e] * demb[d, e]; aux clamp vecs ----
__global__ __launch_bounds__(256) void qdkd_kernel(
    const u16* __restrict__ src, const u16* __restrict__ demb,
    u16* __restrict__ dst, u16* __restrict__ aux0, u16* __restrict__ aux256) {
  const int wt = blockIdx.x * 4 + (threadIdx.x >> 6);
  const int lane = threadIdx.x & 63, lhi = lane >> 4, llo = lane & 15;
  const int m0 = wt << 4;
  short8 a = *reinterpret_cast<const short8*>(&src[(size_t)(m0 + llo) * E_ + lhi * 8]);
#pragma unroll
  for (int ct = 0; ct < 17; ++ct) {
    int d = ct * 16 + llo;
    short8 b = *reinterpret_cast<const short8*>(&demb[d * E_ + lhi * 8]);
    f32x4 c = {};
    c = mfma16(a, b, c);
    if (d < D_) {
#pragma unroll
      for (int r = 0; r < 4; ++r) {
        u16 val = f2bf(c[r] * QSCALE_);
        dst[(size_t)(m0 + lhi * 4 + r) * D_ + d] = val;
        if (d == 0)   aux0[m0 + lhi * 4 + r] = val;
        if (d == 256) aux256[m0 + lhi * 4 + r] = val;
      }
    }
  }
}

// ---- attention (R7, proven 126us): mfma(K,Q) streaming loop ----
// Lane holds S[s=s0+lhi*4+r][q=lg]. ex2 scores, 2-op trunc pack, QD in-kernel,
// far-path clamp vectors from global, XCD swizzle. No barriers; 4 blocks/CU.
__global__ __launch_bounds__(256, 4) void attn_kernel(
    const u16* __restrict__ qw, const u16* __restrict__ kw,
    const u16* __restrict__ vT, const u16* __restrict__ dembp,
    const u16* __restrict__ KDg, const u16* __restrict__ kd0a,
    const u16* __restrict__ kd256a, u16* __restrict__ tb) {
  __shared__ u16 QDs[64 * QDS];   // 32768 B, wave-local
  __shared__ u16 Pbuf[4 * 512];   // 4096 B: per-wave P round-trip (1KB each)
  const int bid = blockIdx.x;
  const int nh = bid & (NH_ - 1);     // XCD-friendly
  const int l0 = (bid >> 7) << 6;
  const int tid = threadIdx.x;
  const int w = tid >> 6, lane = tid & 63, lhi = lane >> 4, llo = lane & 15;
  const int lw0 = l0 + (w << 4);
  const int lg = lw0 + llo;
  const int lrow = (w << 4) + llo;    // this lane's q-row within QDs

  const u16* qb  = qw + (size_t)nh * (L_ * E_);
  const u16* kb  = kw + (size_t)nh * (L_ * E_);
  const u16* vb  = vT + (size_t)nh * (E_ * L_);
  const u16* kdg = KDg + (size_t)nh * ((size_t)L_ * D_);
  const u16* k0g = kd0a + (size_t)nh * L_;
  const u16* k2g = kd256a + (size_t)nh * L_;

  // q fragment (same lane layout works as MFMA A- and B-operand)
  const short8 qA = *(const short8*)&qb[(size_t)lg * E_ + lhi * 8];
  const int qr4 = (w << 4) + (lhi << 2);

  char* Pw = reinterpret_cast<char*>(&Pbuf[w * 512]);

  // in-kernel QD: rows for this wave only; cols 0..255 in LDS
#pragma unroll
  for (int dt = 0; dt < 16; ++dt) {
    short8 db = *(const short8*)&dembp[(dt * 16 + llo) * E_ + lhi * 8];
    f32x4 qd = {};
    qd = mfma16(qA, db, qd);
#pragma unroll
    for (int r = 0; r < 4; ++r)
      QDs[(qr4 + r) * QDS + dt * 16 + llo] = f2bf(qd[r]);
  }
  // col 256 -> register, via one-time per-wave stash in Pw (overwritten later)
  float qd256;
  {
    short8 db = *(const short8*)&dembp[(size_t)(256 + llo) * E_ + lhi * 8];
    f32x4 qd = {};
    qd = mfma16(qA, db, qd);
    u16* stash = reinterpret_cast<u16*>(Pw);
    if (llo == 0) {
#pragma unroll
      for (int r = 0; r < 4; ++r) stash[(lhi << 2) + r] = f2bf(qd[r]);
    }
    qd256 = bf2f(stash[llo]);   // same-wave LDS, lgkm-ordered
  }
  const float qd0 = bf2f(QDs[lrow * QDS + 0]);

  f32x4 o0 = {}, o1 = {};
  float lacc = 0.f;

  for (int s0 = 0; s0 < L_; s0 += 32) {
    short8 kA0 = *(const short8*)&kb[(size_t)(s0 + llo) * E_ + lhi * 8];
    short8 kA1 = *(const short8*)&kb[(size_t)(s0 + 16 + llo) * E_ + lhi * 8];
    f32x4 st0 = {}, st1 = {};
    st0 = mfma16(kA0, qA, st0);
    st1 = mfma16(kA1, qA, st1);

    float p[8];
    const bool far_hi = (lw0 - (s0 + 31)) >= 128;   // all l-s >= 128 -> dd=256
    const bool far_lo = (s0 - (lw0 + 15)) >= 128;   // all s-l >= 128 -> dd=0
    if (far_hi || far_lo) {
      const float qdc = far_hi ? qd256 : qd0;
      const u16* kcg = far_hi ? k2g : k0g;
      u16x4 kc0 = *(const u16x4*)&kcg[s0 + lhi * 4];
      u16x4 kc1 = *(const u16x4*)&kcg[s0 + 16 + lhi * 4];
#pragma unroll
      for (int r = 0; r < 4; ++r) {
        p[r]     = ex2(st0[r] + qdc + bf2f(kc0[r]));
        p[4 + r] = ex2(st1[r] + qdc + bf2f(kc1[r]));
      }
    } else {
#pragma unroll
      for (int i = 0; i < 2; ++i)
#pragma unroll
        for (int r = 0; r < 4; ++r) {
          const int scol = s0 + i * 16 + lhi * 4 + r;
          int d = lg - scol;
          d = (d < -128 ? -128 : (d > 128 ? 128 : d)) + 128;
          int dc = d > 255 ? 255 : d;
          float qd = (d == 256) ? qd256 : bf2f(QDs[lrow * QDS + dc]);
          float kd = bf2f(kdg[(size_t)scol * D_ + d]);
          p[i * 4 + r] = ex2((i ? st1[r] : st0[r]) + qd + kd);
        }
    }
    lacc += ((p[0] + p[1]) + (p[2] + p[3])) + ((p[4] + p[5]) + (p[6] + p[7]));

    // pack P (bf16, trunc-round) into per-wave LDS, XOR-swizzled 8B units
#pragma unroll
    for (int i = 0; i < 2; ++i)
#pragma unroll
      for (int b = 0; b < 2; ++b) {
        union { float f; unsigned u; } a0, a1;
        a0.f = p[i * 4 + 2 * b]; a1.f = p[i * 4 + 2 * b + 1];
        unsigned wv = ((a0.u + 0x8000u) >> 16) | ((a1.u + 0x8000u) & 0xffff0000u);
        int u = (i * 4 + lhi) ^ (llo & 6);
        *reinterpret_cast<unsigned*>(Pw + llo * 64 + u * 8 + b * 4) = wv;
      }
    short8 pB = *reinterpret_cast<const short8*>(
        Pw + llo * 64 + (((lhi * 2) ^ (llo & 6)) * 8));
    short8 vA0 = *(const short8*)&vb[(size_t)llo * L_ + s0 + lhi * 8];
    short8 vA1 = *(const short8*)&vb[(size_t)(16 + llo) * L_ + s0 + lhi * 8];
    o0 = mfma16(vA0, pB, o0);
    o1 = mfma16(vA1, pB, o1);
  }

  // row sum across the 4 lanes sharing llo (lane, lane^16, lane^32, lane^48)
  float l2 = lacc + __shfl_xor(lacc, 16);
  float lt = l2 + __shfl_xor(l2, 32);
  const float inv = 1.0f / lt;

  const int n = nh >> 5, h = nh & 31;
  const size_t obase = (((size_t)((n << 10) | lg)) * 32 + h) * 32;
  u16x4 w0, w1;
#pragma unroll
  for (int r = 0; r < 4; ++r) {
    w0[r] = f2bf(o0[r] * inv);
    w1[r] = f2bf(o1[r] * inv);
  }
  *reinterpret_cast<u16x4*>(&tb[obase + lhi * 4]) = w0;        // e = lhi*4+r
  *reinterpret_cast<u16x4*>(&tb[obase + 16 + lhi * 4]) = w1;   // e = 16+lhi*4+r
}

// ---- AddNorm 1: h = LN(t + x) -> bf16 ----
__global__ __launch_bounds__(256) void ln1_kernel(
    const u16* __restrict__ tbuf, const float* __restrict__ x,
    const float* __restrict__ g, const float* __restrict__ b,
    u16* __restrict__ hb) {
  __shared__ float red[8];
  const int row = blockIdx.x, tid = threadIdx.x;
  const size_t base = (size_t)row * C_ + tid * 4;
  f32x4 xv = *reinterpret_cast<const f32x4*>(&x[base]);
  u16x4 tv = *reinterpret_cast<const u16x4*>(&tbuf[base]);
  float v[4]; float s1 = 0.f, s2 = 0.f;
#pragma unroll
  for (int i = 0; i < 4; ++i) {
    v[i] = xv[i] + bf2f(tv[i]);
    s1 += v[i]; s2 += v[i] * v[i];
  }
#pragma unroll
  for (int off = 32; off >= 1; off >>= 1) {
    s1 += __shfl_xor(s1, off); s2 += __shfl_xor(s2, off);
  }
  if ((tid & 63) == 0) { red[tid >> 6] = s1; red[4 + (tid >> 6)] = s2; }
  __syncthreads();
  float S1 = red[0] + red[1] + red[2] + red[3];
  float S2 = red[4] + red[5] + red[6] + red[7];
  float mu = S1 * (1.f / C_);
  float rs = rsqrtf(S2 * (1.f / C_) - mu * mu + 1e-5f);
#pragma unroll
  for (int i = 0; i < 4; ++i) {
    int c = tid * 4 + i;
    hb[base + i] = f2bf((v[i] - mu) * rs * g[c] + b[c]);
  }
}

// ---- AddNorm 2: out = LN(m + h) -> fp32, transposed (L, N, C) ----
__global__ __launch_bounds__(256) void ln2_kernel(
    const u16* __restrict__ mb, const u16* __restrict__ hb,
    const float* __restrict__ g, const float* __restrict__ b,
    float* __restrict__ out) {
  __shared__ float red[8];
  const int row = blockIdx.x, tid = threadIdx.x;
  const size_t base = (size_t)row * C_ + tid * 4;
  u16x4 mv = *reinterpret_cast<const u16x4*>(&mb[base]);
  u16x4 hv = *reinterpret_cast<const u16x4*>(&hb[base]);
  float v[4]; float s1 = 0.f, s2 = 0.f;
#pragma unroll
  for (int i = 0; i < 4; ++i) {
    v[i] = bf2f(mv[i]) + bf2f(hv[i]);
    s1 += v[i]; s2 += v[i] * v[i];
  }
#pragma unroll
  for (int off = 32; off >= 1; off >>= 1) {
    s1 += __shfl_xor(s1, off); s2 += __shfl_xor(s2, off);
  }
  if ((tid & 63) == 0) { red[tid >> 6] = s1; red[4 + (tid >> 6)] = s2; }
  __syncthreads();
  float S1 = red[0] + red[1] + red[2] + red[3];
  float S2 = red[4] + red[5] + red[6] + red[7];
  float mu = S1 * (1.f / C_);
  float rs = rsqrtf(S2 * (1.f / C_) - mu * mu + 1e-5f);
  const int n = row >> 10, l = row & 1023;
  const size_t ob = (size_t)(l * N_ + n) * C_ + tid * 4;
#pragma unroll
  for (int i = 0; i < 4; ++i) {
    int c = tid * 4 + i;
    out[ob + i] = (v[i] - mu) * rs * g[c] + b[c];
  }
}

extern "C" void kernel_launch(void* const* d_in, const int* in_sizes, int n_in,
                              void* d_out, int out_size, void* d_ws, size_t ws_size,
                              hipStream_t stream) {
  const float* x    = (const float*)d_in[0];
  const float* Wq   = (const float*)d_in[1];
  const float* bq   = (const float*)d_in[2];
  const float* Wk   = (const float*)d_in[3];
  const float* bk   = (const float*)d_in[4];
  const float* Wv   = (const float*)d_in[5];
  const float* bv   = (const float*)d_in[6];
  const float* demb = (const float*)d_in[7];
  const float* g1   = (const float*)d_in[8];
  const float* b1ln = (const float*)d_in[9];
  const float* g2   = (const float*)d_in[10];
  const float* b2ln = (const float*)d_in[11];
  const float* W1   = (const float*)d_in[12];
  const float* b1   = (const float*)d_in[13];
  const float* W2   = (const float*)d_in[14];
  const float* b2   = (const float*)d_in[15];
  float* outp = (float*)d_out;

  size_t o = 0;
  auto alloc = [&](size_t bytes) { size_t r = o; o += (bytes + 255) & ~(size_t)255; return r; };
  const size_t xb_o    = alloc((size_t)M_ * C_ * 2);
  const size_t wqkv_o  = alloc((size_t)3 * C_ * C_ * 2);   // contiguous with w1,w2
  const size_t w1_o    = alloc((size_t)C_ * C_ * 2);
  const size_t w2_o    = alloc((size_t)C_ * C_ * 2);
  const size_t bqkv_o  = alloc((size_t)3 * C_ * 4);
  const size_t demb_o  = alloc((size_t)DPAD * E_ * 2);
  const size_t q_o     = alloc((size_t)NH_ * L_ * E_ * 2);
  const size_t k_o     = alloc((size_t)NH_ * L_ * E_ * 2);
  const size_t vt_o    = alloc((size_t)NH_ * L_ * E_ * 2);
  const size_t kd_o    = alloc((size_t)NH_ * L_ * D_ * 2);
  const size_t kd0_o   = alloc((size_t)NH_ * L_ * 2);
  const size_t kd256_o = alloc((size_t)NH_ * L_ * 2);
  const size_t t_o     = alloc((size_t)M_ * C_ * 2);
  const size_t h_o     = alloc((size_t)M_ * C_ * 2);
  const size_t m1_o    = alloc((size_t)M_ * C_ * 2);
  const size_t m_o     = alloc((size_t)M_ * C_ * 2);
  if (o > ws_size) return;  // ws too small -> visible zero-output failure

  char* ws = (char*)d_ws;
  u16*   xb     = (u16*)(ws + xb_o);
  u16*   wqkv_t = (u16*)(ws + wqkv_o);
  u16*   w1_t   = (u16*)(ws + w1_o);
  u16*   w2_t   = (u16*)(ws + w2_o);
  float* bqkv   = (float*)(ws + bqkv_o);
  u16*   demb_b = (u16*)(ws + demb_o);
  u16*   q_ws   = (u16*)(ws + q_o);
  u16*   k_ws   = (u16*)(ws + k_o);
  u16*   vT_ws  = (u16*)(ws + vt_o);
  u16*   KD     = (u16*)(ws + kd_o);
  u16*   kd0a   = (u16*)(ws + kd0_o);
  u16*   kd256a = (u16*)(ws + kd256_o);
  u16*   t_b16  = (u16*)(ws + t_o);
  u16*   h_b16  = (u16*)(ws + h_o);
  u16*   m1_b16 = (u16*)(ws + m1_o);
  u16*   m_b16  = (u16*)(ws + m_o);

  misc_kernel<<<4096 + 34, 256, 0, stream>>>(x, demb, bq, bk, bv, xb, demb_b, bqkv);
  dim3 tb_(32, 8), tg_(32, 32, 5);
  transpose_w_kernel<<<tg_, tb_, 0, stream>>>(Wq, Wk, Wv, W1, W2, wqkv_t);

  gemm128_kernel<0><<<32 * 24, 256, 0, stream>>>(xb, wqkv_t, C_, bqkv, q_ws, k_ws, vT_ws);

  qdkd_kernel<<<2048, 256, 0, stream>>>(k_ws, demb_b, KD, kd0a, kd256a);

  attn_kernel<<<NH_ * 16, 256, 0, stream>>>(q_ws, k_ws, vT_ws, demb_b, KD, kd0a, kd256a, t_b16);

  ln1_kernel<<<M_, 256, 0, stream>>>(t_b16, x, g1, b1ln, h_b16);

  gemm64_kernel<1><<<64 * 8, 256, 0, stream>>>(h_b16, w1_t, C_, b1, m1_b16);
  gemm64_kernel<2><<<64 * 8, 256, 0, stream>>>(m1_b16, w2_t, C_, b2, m_b16);

  ln2_kernel<<<M_, 256, 0, stream>>>(m_b16, h_b16, g2, b2ln, outp);
}

// Round 12
// 263.035 us; speedup vs baseline: 1.2320x; 1.0064x over previous
//
#include <hip/hip_runtime.h>

#define H_ 32
#define E_ 32
#define C_ 1024
#define L_ 1024
#define N_ 4
#define M_ 4096      // N_*L_
#define NH_ 128      // N_*H_
#define D_ 257
#define DPAD 272     // demb padded rows (zeros beyond 256)
#define QDS 256      // QD row stride in LDS (col 256 lives in a register)
#define TEMP_ 0.17677669529663687f
#define QSCALE_ (TEMP_ * 1.4426950408889634f)   // temp * log2(e), folded into q & KD

typedef unsigned short u16;
typedef __attribute__((ext_vector_type(8))) short short8;
typedef __attribute__((ext_vector_type(4))) float f32x4;
typedef __attribute__((ext_vector_type(4))) unsigned short u16x4;

__device__ __forceinline__ u16 f2bf(float f) {
  union { float f; unsigned u; } v; v.f = f;
  unsigned r = v.u + 0x7fffu + ((v.u >> 16) & 1u);
  return (u16)(r >> 16);
}
__device__ __forceinline__ float bf2f(u16 h) {
  union { unsigned u; float f; } v; v.u = ((unsigned)h) << 16;
  return v.f;
}
__device__ __forceinline__ f32x4 mfma16(short8 a, short8 b, f32x4 c) {
  return __builtin_amdgcn_mfma_f32_16x16x32_bf16(a, b, c, 0, 0, 0);
}
__device__ __forceinline__ float ex2(float x) {
#if __has_builtin(__builtin_amdgcn_exp2f)
  return __builtin_amdgcn_exp2f(x);
#else
  float r;
  asm("v_exp_f32 %0, %1\n\ts_nop 1" : "=v"(r) : "v"(x));
  return r;
#endif
}
// async global->LDS, 16B per lane; lds base must be wave-uniform
__device__ __forceinline__ void gld16(const u16* g, u16* l) {
  __builtin_amdgcn_global_load_lds(
      (const __attribute__((address_space(1))) unsigned int*)g,
      (__attribute__((address_space(3))) unsigned int*)l, 16, 0, 0);
}

// ---- misc: x->bf16 conversion + dist_emb->bf16 (padded) + qkv bias pack ----
__global__ __launch_bounds__(256) void misc_kernel(
    const float* __restrict__ x, const float* __restrict__ demb,
    const float* __restrict__ bq, const float* __restrict__ bk,
    const float* __restrict__ bv, u16* __restrict__ xb,
    u16* __restrict__ demb_b, float* __restrict__ bqkv) {
  const int b = blockIdx.x, tid = threadIdx.x;
  if (b < 4096) {
    int i = b * 256 + tid;
    f32x4 v = reinterpret_cast<const f32x4*>(x)[i];
    u16x4 o2;
    o2[0] = f2bf(v[0]); o2[1] = f2bf(v[1]); o2[2] = f2bf(v[2]); o2[3] = f2bf(v[3]);
    reinterpret_cast<u16x4*>(xb)[i] = o2;
  } else {
    int i = (b - 4096) * 256 + tid;
    if (i < DPAD * E_) demb_b[i] = (i < D_ * E_) ? f2bf(demb[i]) : (u16)0;
    if (i < C_) { bqkv[i] = bq[i]; bqkv[C_ + i] = bk[i]; bqkv[2 * C_ + i] = bv[i]; }
  }
}

// ---- 5 weight transposes in one launch: W (K x N) -> W^T (N x K) bf16 ----
__global__ __launch_bounds__(256) void transpose_w_kernel(
    const float* __restrict__ Wq, const float* __restrict__ Wk,
    const float* __restrict__ Wv, const float* __restrict__ W1,
    const float* __restrict__ W2, u16* __restrict__ out_base) {
  __shared__ float tile[32][33];
  const int z = blockIdx.z;
  const float* in = (z == 0) ? Wq : (z == 1) ? Wk : (z == 2) ? Wv : (z == 3) ? W1 : W2;
  u16* out = out_base + (size_t)z * C_ * C_;
  int j0 = blockIdx.x * 32, c0 = blockIdx.y * 32;
#pragma unroll
  for (int i = 0; i < 4; ++i) {
    int cy = threadIdx.y + i * 8;
    tile[cy][threadIdx.x] = in[(size_t)(c0 + cy) * C_ + j0 + threadIdx.x];
  }
  __syncthreads();
#pragma unroll
  for (int i = 0; i < 4; ++i) {
    int jy = threadIdx.y + i * 8;
    out[(size_t)(j0 + jy) * C_ + c0 + threadIdx.x] = f2bf(tile[threadIdx.x][jy]);
  }
}

// ---- GEMM 128x128: C = A * Bt^T, bf16 in / fp32 acc (qkv projection) ----
template <int EPI>
__global__ __launch_bounds__(256) void gemm128_kernel(
    const u16* __restrict__ A, const u16* __restrict__ Bt, int K,
    const float* __restrict__ bias,
    u16* __restrict__ out0, u16* __restrict__ out1, u16* __restrict__ out2) {
  __shared__ u16 As[128 * 64];
  __shared__ u16 Bs[128 * 64];
  const int bid = blockIdx.x;
  const int m0 = (bid & 31) << 7;
  const int n0 = (bid >> 5) << 7;
  const int tid = threadIdx.x;
  const int w = tid >> 6, lane = tid & 63, lhi = lane >> 4, llo = lane & 15;
  const int wr = w >> 1, wc = w & 1;
  const int w4 = w << 2;
  const int srow = lane >> 3, scol = (lane & 7) << 3;
  f32x4 acc[4][4] = {};
  for (int k0 = 0; k0 < K; k0 += 64) {
#pragma unroll
    for (int j = 0; j < 4; ++j) {
      const int seg = w4 + j;
      const int row = (seg << 3) + srow;
      gld16(&A[(size_t)(m0 + row) * K + k0 + scol], &As[seg << 9]);
      gld16(&Bt[(size_t)(n0 + row) * K + k0 + scol], &Bs[seg << 9]);
    }
    __syncthreads();
#pragma unroll
    for (int kk = 0; kk < 2; ++kk) {
      const int ko = (kk << 5) + lhi * 8;
      short8 af[4], bf[4];
#pragma unroll
      for (int mi = 0; mi < 4; ++mi)
        af[mi] = *reinterpret_cast<const short8*>(&As[(wr * 64 + mi * 16 + llo) * 64 + ko]);
#pragma unroll
      for (int ni = 0; ni < 4; ++ni)
        bf[ni] = *reinterpret_cast<const short8*>(&Bs[(wc * 64 + ni * 16 + llo) * 64 + ko]);
#pragma unroll
      for (int mi = 0; mi < 4; ++mi)
#pragma unroll
        for (int ni = 0; ni < 4; ++ni)
          acc[mi][ni] = mfma16(af[mi], bf[ni], acc[mi][ni]);
    }
    __syncthreads();
  }
#pragma unroll
  for (int mi = 0; mi < 4; ++mi)
#pragma unroll
    for (int ni = 0; ni < 4; ++ni)
#pragma unroll
      for (int r = 0; r < 4; ++r) {
        int row = m0 + wr * 64 + mi * 16 + lhi * 4 + r;
        int col = n0 + wc * 64 + ni * 16 + llo;
        float v = acc[mi][ni][r] + bias[col];
        if constexpr (EPI == 0) {
          int which = col >> 10, jj = col & 1023, h = jj >> 5, e2 = jj & 31;
          int n = row >> 10, l = row & 1023;
          int nh = (n << 5) | h;
          if (which == 0) v *= QSCALE_;   // fold temp*log2e into q
          u16 bvv = f2bf(v);
          if (which == 0)      out0[((size_t)((nh << 10) | l)) * 32 + e2] = bvv;
          else if (which == 1) out1[((size_t)((nh << 10) | l)) * 32 + e2] = bvv;
          else                 out2[(((size_t)(nh * 32 + e2)) << 10) | l] = bvv;
        } else if constexpr (EPI == 1) {
          out0[(size_t)row * C_ + col] = f2bf(fmaxf(v, 0.f));
        } else {
          out0[(size_t)row * C_ + col] = f2bf(v);
        }
      }
}

// ---- GEMM 64x128 (MLP): 512 blocks -> 2 blocks/CU ----
template <int EPI>
__global__ __launch_bounds__(256, 4) void gemm64_kernel(
    const u16* __restrict__ A, const u16* __restrict__ Bt, int K,
    const float* __restrict__ bias, u16* __restrict__ out0) {
  __shared__ u16 As[64 * 64];     // 8192 B
  __shared__ u16 Bs[128 * 64];    // 16384 B
  const int bid = blockIdx.x;
  const int m0 = (bid & 63) << 6;
  const int n0 = (bid >> 6) << 7;
  const int tid = threadIdx.x;
  const int w = tid >> 6, lane = tid & 63, lhi = lane >> 4, llo = lane & 15;
  const int wr = w >> 1, wc = w & 1;   // wr: 32-row half, wc: 64-col half
  const int srow = lane >> 3, scol = (lane & 7) << 3;
  f32x4 acc[2][4] = {};
  for (int k0 = 0; k0 < K; k0 += 64) {
#pragma unroll
    for (int j = 0; j < 2; ++j) {       // A: 8 segs of 8 rows
      const int seg = w * 2 + j;
      const int row = (seg << 3) + srow;
      gld16(&A[(size_t)(m0 + row) * K + k0 + scol], &As[seg << 9]);
    }
#pragma unroll
    for (int j = 0; j < 4; ++j) {       // B: 16 segs of 8 rows
      const int seg = w * 4 + j;
      const int row = (seg << 3) + srow;
      gld16(&Bt[(size_t)(n0 + row) * K + k0 + scol], &Bs[seg << 9]);
    }
    __syncthreads();
#pragma unroll
    for (int kk = 0; kk < 2; ++kk) {
      const int ko = (kk << 5) + lhi * 8;
      short8 af[2], bf[4];
#pragma unroll
      for (int mi = 0; mi < 2; ++mi)
        af[mi] = *reinterpret_cast<const short8*>(&As[(wr * 32 + mi * 16 + llo) * 64 + ko]);
#pragma unroll
      for (int ni = 0; ni < 4; ++ni)
        bf[ni] = *reinterpret_cast<const short8*>(&Bs[(wc * 64 + ni * 16 + llo) * 64 + ko]);
#pragma unroll
      for (int mi = 0; mi < 2; ++mi)
#pragma unroll
        for (int ni = 0; ni < 4; ++ni)
          acc[mi][ni] = mfma16(af[mi], bf[ni], acc[mi][ni]);
    }
    __syncthreads();
  }
#pragma unroll
  for (int mi = 0; mi < 2; ++mi)
#pragma unroll
    for (int ni = 0; ni < 4; ++ni)
#pragma unroll
      for (int r = 0; r < 4; ++r) {
        int row = m0 + wr * 32 + mi * 16 + lhi * 4 + r;
        int col = n0 + wc * 64 + ni * 16 + llo;
        float v = acc[mi][ni][r] + bias[col];
        if constexpr (EPI == 1) out0[(size_t)row * C_ + col] = f2bf(fmaxf(v, 0.f));
        else                    out0[(size_t)row * C_ + col] = f2bf(v);
      }
}

// ---- KD: dst[m, d] = QSCALE * sum_e k[m, e] * demb[d, e]; aux clamp vecs ----
__global__ __launch_bounds__(256) void qdkd_kernel(
    const u16* __restrict__ src, const u16* __restrict__ demb,
    u16* __restrict__ dst, u16* __restrict__ aux0, u16* __restrict__ aux256) {
  const int wt = blockIdx.x * 4 + (threadIdx.x >> 6);
  const int lane = threadIdx.x & 63, lhi = lane >> 4, llo = lane & 15;
  const int m0 = wt << 4;
  short8 a = *reinterpret_cast<const short8*>(&src[(size_t)(m0 + llo) * E_ + lhi * 8]);
#pragma unroll
  for (int ct = 0; ct < 17; ++ct) {
    int d = ct * 16 + llo;
    short8 b = *reinterpret_cast<const short8*>(&demb[d * E_ + lhi * 8]);
    f32x4 c = {};
    c = mfma16(a, b, c);
    if (d < D_) {
#pragma unroll
      for (int r = 0; r < 4; ++r) {
        u16 val = f2bf(c[r] * QSCALE_);
        dst[(size_t)(m0 + lhi * 4 + r) * D_ + d] = val;
        if (d == 0)   aux0[m0 + lhi * 4 + r] = val;
        if (d == 256) aux256[m0 + lhi * 4 + r] = val;
      }
    }
  }
}

// ---- attention v12: R7 loop manually unrolled x2, disjoint P buffers ----
// Two independent tiles per iteration (A: s0, B: s0+32) -> textual ILP the
// compiler can schedule without cross-iteration alias analysis. LDS 40960 B
// (QDs 32K + Pbuf 8K) = exactly 4 blocks/CU. No barriers.
__global__ __launch_bounds__(256, 4) void attn_kernel(
    const u16* __restrict__ qw, const u16* __restrict__ kw,
    const u16* __restrict__ vT, const u16* __restrict__ dembp,
    const u16* __restrict__ KDg, const u16* __restrict__ kd0a,
    const u16* __restrict__ kd256a, u16* __restrict__ tb) {
  __shared__ u16 QDs[64 * QDS];   // 32768 B, wave-local
  __shared__ u16 Pbuf[4 * 1024];  // 8192 B: per-wave 2KB = two 1KB P buffers
  const int bid = blockIdx.x;
  const int nh = bid & (NH_ - 1);     // XCD-friendly
  const int l0 = (bid >> 7) << 6;
  const int tid = threadIdx.x;
  const int w = tid >> 6, lane = tid & 63, lhi = lane >> 4, llo = lane & 15;
  const int lw0 = l0 + (w << 4);
  const int lg = lw0 + llo;
  const int lrow = (w << 4) + llo;    // this lane's q-row within QDs

  const u16* qb  = qw + (size_t)nh * (L_ * E_);
  const u16* kb  = kw + (size_t)nh * (L_ * E_);
  const u16* vb  = vT + (size_t)nh * (E_ * L_);
  const u16* kdg = KDg + (size_t)nh * ((size_t)L_ * D_);
  const u16* k0g = kd0a + (size_t)nh * L_;
  const u16* k2g = kd256a + (size_t)nh * L_;

  const short8 qA = *(const short8*)&qb[(size_t)lg * E_ + lhi * 8];
  const int qr4 = (w << 4) + (lhi << 2);

  char* Pw = reinterpret_cast<char*>(&Pbuf[w * 1024]);   // 2KB region

  // in-kernel QD: rows for this wave only; cols 0..255 in LDS
#pragma unroll
  for (int dt = 0; dt < 16; ++dt) {
    short8 db = *(const short8*)&dembp[(dt * 16 + llo) * E_ + lhi * 8];
    f32x4 qd = {};
    qd = mfma16(qA, db, qd);
#pragma unroll
    for (int r = 0; r < 4; ++r)
      QDs[(qr4 + r) * QDS + dt * 16 + llo] = f2bf(qd[r]);
  }
  // col 256 -> register, via one-time per-wave stash in Pw (overwritten later)
  float qd256;
  {
    short8 db = *(const short8*)&dembp[(size_t)(256 + llo) * E_ + lhi * 8];
    f32x4 qd = {};
    qd = mfma16(qA, db, qd);
    u16* stash = reinterpret_cast<u16*>(Pw);
    if (llo == 0) {
#pragma unroll
      for (int r = 0; r < 4; ++r) stash[(lhi << 2) + r] = f2bf(qd[r]);
    }
    qd256 = bf2f(stash[llo]);   // same-wave LDS, lgkm-ordered
  }
  const float qd0 = bf2f(QDs[lrow * QDS + 0]);

  f32x4 o0 = {}, o1 = {};
  float lacc = 0.f;

  // score assembly for tile at S0 (K-frag results ST0/ST1) -> P[8]
#define ASM_SCORE(S0, ST0, ST1, P)                                             \
  {                                                                            \
    const int s0_ = (S0);                                                      \
    const bool far_hi = (lw0 - (s0_ + 31)) >= 128;                             \
    const bool far_lo = (s0_ - (lw0 + 15)) >= 128;                             \
    if (far_hi || far_lo) {                                                    \
      const float qdc = far_hi ? qd256 : qd0;                                  \
      const u16* kcg = far_hi ? k2g : k0g;                                     \
      u16x4 kc0 = *(const u16x4*)&kcg[s0_ + lhi * 4];                          \
      u16x4 kc1 = *(const u16x4*)&kcg[s0_ + 16 + lhi * 4];                     \
      _Pragma("unroll") for (int r = 0; r < 4; ++r) {                          \
        P[r]     = ex2(ST0[r] + qdc + bf2f(kc0[r]));                           \
        P[4 + r] = ex2(ST1[r] + qdc + bf2f(kc1[r]));                           \
      }                                                                        \
    } else {                                                                   \
      _Pragma("unroll") for (int i = 0; i < 2; ++i)                            \
        _Pragma("unroll") for (int r = 0; r < 4; ++r) {                        \
          const int scol = s0_ + i * 16 + lhi * 4 + r;                         \
          int d = lg - scol;                                                   \
          d = (d < -128 ? -128 : (d > 128 ? 128 : d)) + 128;                   \
          int dc = d > 255 ? 255 : d;                                          \
          float qd = (d == 256) ? qd256 : bf2f(QDs[lrow * QDS + dc]);          \
          float kd = bf2f(kdg[(size_t)scol * D_ + d]);                         \
          P[i * 4 + r] = ex2((i ? ST1[r] : ST0[r]) + qd + kd);                 \
        }                                                                      \
    }                                                                          \
  }

#define PACKP(P, OFF)                                                          \
  _Pragma("unroll") for (int i = 0; i < 2; ++i)                                \
    _Pragma("unroll") for (int b = 0; b < 2; ++b) {                            \
      union { float f; unsigned u; } a0_, a1_;                                 \
      a0_.f = P[i * 4 + 2 * b]; a1_.f = P[i * 4 + 2 * b + 1];                  \
      unsigned wv_ = ((a0_.u + 0x8000u) >> 16) | ((a1_.u + 0x8000u) & 0xffff0000u); \
      int u_ = (i * 4 + lhi) ^ (llo & 6);                                      \
      *reinterpret_cast<unsigned*>(Pw + (OFF) + llo * 64 + u_ * 8 + b * 4) = wv_; \
    }

  for (int s0 = 0; s0 < L_; s0 += 64) {
    const int sb = s0 + 32;
    // all global loads for both tiles up front (independent)
    short8 kA0a = *(const short8*)&kb[(size_t)(s0 + llo) * E_ + lhi * 8];
    short8 kA1a = *(const short8*)&kb[(size_t)(s0 + 16 + llo) * E_ + lhi * 8];
    short8 kA0b = *(const short8*)&kb[(size_t)(sb + llo) * E_ + lhi * 8];
    short8 kA1b = *(const short8*)&kb[(size_t)(sb + 16 + llo) * E_ + lhi * 8];
    short8 vA0a = *(const short8*)&vb[(size_t)llo * L_ + s0 + lhi * 8];
    short8 vA1a = *(const short8*)&vb[(size_t)(16 + llo) * L_ + s0 + lhi * 8];
    short8 vA0b = *(const short8*)&vb[(size_t)llo * L_ + sb + lhi * 8];
    short8 vA1b = *(const short8*)&vb[(size_t)(16 + llo) * L_ + sb + lhi * 8];

    f32x4 st0a = {}, st1a = {}, st0b = {}, st1b = {};
    st0a = mfma16(kA0a, qA, st0a);
    st1a = mfma16(kA1a, qA, st1a);
    st0b = mfma16(kA0b, qA, st0b);
    st1b = mfma16(kA1b, qA, st1b);

    float pa[8], pb[8];
    ASM_SCORE(s0, st0a, st1a, pa);
    ASM_SCORE(sb, st0b, st1b, pb);

    lacc += ((pa[0] + pa[1]) + (pa[2] + pa[3])) + ((pa[4] + pa[5]) + (pa[6] + pa[7]));
    lacc += ((pb[0] + pb[1]) + (pb[2] + pb[3])) + ((pb[4] + pb[5]) + (pb[6] + pb[7]));

    PACKP(pa, 0);
    PACKP(pb, 1024);

    short8 pBa = *reinterpret_cast<const short8*>(
        Pw + llo * 64 + (((lhi * 2) ^ (llo & 6)) * 8));
    short8 pBb = *reinterpret_cast<const short8*>(
        Pw + 1024 + llo * 64 + (((lhi * 2) ^ (llo & 6)) * 8));
    o0 = mfma16(vA0a, pBa, o0);
    o1 = mfma16(vA1a, pBa, o1);
    o0 = mfma16(vA0b, pBb, o0);
    o1 = mfma16(vA1b, pBb, o1);
  }
#undef ASM_SCORE
#undef PACKP

  // row sum across the 4 lanes sharing llo (lane, lane^16, lane^32, lane^48)
  float l2 = lacc + __shfl_xor(lacc, 16);
  float lt = l2 + __shfl_xor(l2, 32);
  const float inv = 1.0f / lt;

  const int n = nh >> 5, h = nh & 31;
  const size_t obase = (((size_t)((n << 10) | lg)) * 32 + h) * 32;
  u16x4 w0, w1;
#pragma unroll
  for (int r = 0; r < 4; ++r) {
    w0[r] = f2bf(o0[r] * inv);
    w1[r] = f2bf(o1[r] * inv);
  }
  *reinterpret_cast<u16x4*>(&tb[obase + lhi * 4]) = w0;        // e = lhi*4+r
  *reinterpret_cast<u16x4*>(&tb[obase + 16 + lhi * 4]) = w1;   // e = 16+lhi*4+r
}

// ---- AddNorm 1: h = LN(t + x) -> bf16 ----
__global__ __launch_bounds__(256) void ln1_kernel(
    const u16* __restrict__ tbuf, const float* __restrict__ x,
    const float* __restrict__ g, const float* __restrict__ b,
    u16* __restrict__ hb) {
  __shared__ float red[8];
  const int row = blockIdx.x, tid = threadIdx.x;
  const size_t base = (size_t)row * C_ + tid * 4;
  f32x4 xv = *reinterpret_cast<const f32x4*>(&x[base]);
  u16x4 tv = *reinterpret_cast<const u16x4*>(&tbuf[base]);
  float v[4]; float s1 = 0.f, s2 = 0.f;
#pragma unroll
  for (int i = 0; i < 4; ++i) {
    v[i] = xv[i] + bf2f(tv[i]);
    s1 += v[i]; s2 += v[i] * v[i];
  }
#pragma unroll
  for (int off = 32; off >= 1; off >>= 1) {
    s1 += __shfl_xor(s1, off); s2 += __shfl_xor(s2, off);
  }
  if ((tid & 63) == 0) { red[tid >> 6] = s1; red[4 + (tid >> 6)] = s2; }
  __syncthreads();
  float S1 = red[0] + red[1] + red[2] + red[3];
  float S2 = red[4] + red[5] + red[6] + red[7];
  float mu = S1 * (1.f / C_);
  float rs = rsqrtf(S2 * (1.f / C_) - mu * mu + 1e-5f);
#pragma unroll
  for (int i = 0; i < 4; ++i) {
    int c = tid * 4 + i;
    hb[base + i] = f2bf((v[i] - mu) * rs * g[c] + b[c]);
  }
}

// ---- AddNorm 2: out = LN(m + h) -> fp32, transposed (L, N, C) ----
__global__ __launch_bounds__(256) void ln2_kernel(
    const u16* __restrict__ mb, const u16* __restrict__ hb,
    const float* __restrict__ g, const float* __restrict__ b,
    float* __restrict__ out) {
  __shared__ float red[8];
  const int row = blockIdx.x, tid = threadIdx.x;
  const size_t base = (size_t)row * C_ + tid * 4;
  u16x4 mv = *reinterpret_cast<const u16x4*>(&mb[base]);
  u16x4 hv = *reinterpret_cast<const u16x4*>(&hb[base]);
  float v[4]; float s1 = 0.f, s2 = 0.f;
#pragma unroll
  for (int i = 0; i < 4; ++i) {
    v[i] = bf2f(mv[i]) + bf2f(hv[i]);
    s1 += v[i]; s2 += v[i] * v[i];
  }
#pragma unroll
  for (int off = 32; off >= 1; off >>= 1) {
    s1 += __shfl_xor(s1, off); s2 += __shfl_xor(s2, off);
  }
  if ((tid & 63) == 0) { red[tid >> 6] = s1; red[4 + (tid >> 6)] = s2; }
  __syncthreads();
  float S1 = red[0] + red[1] + red[2] + red[3];
  float S2 = red[4] + red[5] + red[6] + red[7];
  float mu = S1 * (1.f / C_);
  float rs = rsqrtf(S2 * (1.f / C_) - mu * mu + 1e-5f);
  const int n = row >> 10, l = row & 1023;
  const size_t ob = (size_t)(l * N_ + n) * C_ + tid * 4;
#pragma unroll
  for (int i = 0; i < 4; ++i) {
    int c = tid * 4 + i;
    out[ob + i] = (v[i] - mu) * rs * g[c] + b[c];
  }
}

extern "C" void kernel_launch(void* const* d_in, const int* in_sizes, int n_in,
                              void* d_out, int out_size, void* d_ws, size_t ws_size,
                              hipStream_t stream) {
  const float* x    = (const float*)d_in[0];
  const float* Wq   = (const float*)d_in[1];
  const float* bq   = (const float*)d_in[2];
  const float* Wk   = (const float*)d_in[3];
  const float* bk   = (const float*)d_in[4];
  const float* Wv   = (const float*)d_in[5];
  const float* bv   = (const float*)d_in[6];
  const float* demb = (const float*)d_in[7];
  const float* g1   = (const float*)d_in[8];
  const float* b1ln = (const float*)d_in[9];
  const float* g2   = (const float*)d_in[10];
  const float* b2ln = (const float*)d_in[11];
  const float* W1   = (const float*)d_in[12];
  const float* b1   = (const float*)d_in[13];
  const float* W2   = (const float*)d_in[14];
  const float* b2   = (const float*)d_in[15];
  float* outp = (float*)d_out;

  size_t o = 0;
  auto alloc = [&](size_t bytes) { size_t r = o; o += (bytes + 255) & ~(size_t)255; return r; };
  const size_t xb_o    = alloc((size_t)M_ * C_ * 2);
  const size_t wqkv_o  = alloc((size_t)3 * C_ * C_ * 2);   // contiguous with w1,w2
  const size_t w1_o    = alloc((size_t)C_ * C_ * 2);
  const size_t w2_o    = alloc((size_t)C_ * C_ * 2);
  const size_t bqkv_o  = alloc((size_t)3 * C_ * 4);
  const size_t demb_o  = alloc((size_t)DPAD * E_ * 2);
  const size_t q_o     = alloc((size_t)NH_ * L_ * E_ * 2);
  const size_t k_o     = alloc((size_t)NH_ * L_ * E_ * 2);
  const size_t vt_o    = alloc((size_t)NH_ * L_ * E_ * 2);
  const size_t kd_o    = alloc((size_t)NH_ * L_ * D_ * 2);
  const size_t kd0_o   = alloc((size_t)NH_ * L_ * 2);
  const size_t kd256_o = alloc((size_t)NH_ * L_ * 2);
  const size_t t_o     = alloc((size_t)M_ * C_ * 2);
  const size_t h_o     = alloc((size_t)M_ * C_ * 2);
  const size_t m1_o    = alloc((size_t)M_ * C_ * 2);
  const size_t m_o     = alloc((size_t)M_ * C_ * 2);
  if (o > ws_size) return;  // ws too small -> visible zero-output failure

  char* ws = (char*)d_ws;
  u16*   xb     = (u16*)(ws + xb_o);
  u16*   wqkv_t = (u16*)(ws + wqkv_o);
  u16*   w1_t   = (u16*)(ws + w1_o);
  u16*   w2_t   = (u16*)(ws + w2_o);
  float* bqkv   = (float*)(ws + bqkv_o);
  u16*   demb_b = (u16*)(ws + demb_o);
  u16*   q_ws   = (u16*)(ws + q_o);
  u16*   k_ws   = (u16*)(ws + k_o);
  u16*   vT_ws  = (u16*)(ws + vt_o);
  u16*   KD     = (u16*)(ws + kd_o);
  u16*   kd0a   = (u16*)(ws + kd0_o);
  u16*   kd256a = (u16*)(ws + kd256_o);
  u16*   t_b16  = (u16*)(ws + t_o);
  u16*   h_b16  = (u16*)(ws + h_o);
  u16*   m1_b16 = (u16*)(ws + m1_o);
  u16*   m_b16  = (u16*)(ws + m_o);

  misc_kernel<<<4096 + 34, 256, 0, stream>>>(x, demb, bq, bk, bv, xb, demb_b, bqkv);
  dim3 tb_(32, 8), tg_(32, 32, 5);
  transpose_w_kernel<<<tg_, tb_, 0, stream>>>(Wq, Wk, Wv, W1, W2, wqkv_t);

  gemm128_kernel<0><<<32 * 24, 256, 0, stream>>>(xb, wqkv_t, C_, bqkv, q_ws, k_ws, vT_ws);

  qdkd_kernel<<<2048, 256, 0, stream>>>(k_ws, demb_b, KD, kd0a, kd256a);

  attn_kernel<<<NH_ * 16, 256, 0, stream>>>(q_ws, k_ws, vT_ws, demb_b, KD, kd0a, kd256a, t_b16);

  ln1_kernel<<<M_, 256, 0, stream>>>(t_b16, x, g1, b1ln, h_b16);

  gemm64_kernel<1><<<64 * 8, 256, 0, stream>>>(h_b16, w1_t, C_, b1, m1_b16);
  gemm64_kernel<2><<<64 * 8, 256, 0, stream>>>(m1_b16, w2_t, C_, b2, m_b16);

  ln2_kernel<<<M_, 256, 0, stream>>>(m_b16, h_b16, g2, b2ln, outp);
}